// Round 17
// baseline (521.721 us; speedup 1.0000x reference)
//
#include <hip/hip_runtime.h>

// ============ CSR build (both directions, one pass, no global atomics) ============
#define CSR_B 128

__global__ __launch_bounds__(256) void k_hist2(const int* __restrict__ eidx, int E, int N,
                                               int* __restrict__ partial_d,
                                               int* __restrict__ partial_s) {
  extern __shared__ unsigned int hist[];  // [2*nw]
  int nw = (N + 1) >> 1;
  for (int i = threadIdx.x; i < 2 * nw; i += blockDim.x) hist[i] = 0u;
  __syncthreads();
  const int* src = eidx;
  const int* dst = eidx + E;
  int chunk = (E + CSR_B - 1) / CSR_B;
  int beg = blockIdx.x * chunk, end = min(E, beg + chunk);
  for (int e = beg + threadIdx.x; e < end; e += blockDim.x) {
    int d = dst[e];
    atomicAdd(&hist[d >> 1], 1u << ((d & 1) * 16));
    int s = src[e];
    atomicAdd(&hist[nw + (s >> 1)], 1u << ((s & 1) * 16));
  }
  __syncthreads();
  for (int i = threadIdx.x; i < N; i += blockDim.x) {
    partial_d[(size_t)blockIdx.x * N + i] = (int)((hist[i >> 1] >> ((i & 1) * 16)) & 0xFFFFu);
    partial_s[(size_t)blockIdx.x * N + i] = (int)((hist[nw + (i >> 1)] >> ((i & 1) * 16)) & 0xFFFFu);
  }
}

__global__ __launch_bounds__(256) void k_colscan2(int* __restrict__ partial_d,
                                                  int* __restrict__ cnt_d,
                                                  int* __restrict__ partial_s,
                                                  int* __restrict__ cnt_s, int N) {
  int g = blockIdx.x * blockDim.x + threadIdx.x;
  int* partial;
  int* cnt;
  int bin;
  if (g < N) { partial = partial_d; cnt = cnt_d; bin = g; }
  else if (g < 2 * N) { partial = partial_s; cnt = cnt_s; bin = g - N; }
  else return;
  int run = 0;
  for (int b = 0; b < CSR_B; ++b) {
    int t = partial[(size_t)b * N + bin];
    partial[(size_t)b * N + bin] = run;
    run += t;
  }
  cnt[bin] = run;
}

// ============ hierarchical scan ============
#define SCAN_CHUNK 2048

__global__ __launch_bounds__(256) void k_bsum(const int* __restrict__ cnt_d,
                                              const int* __restrict__ cnt_s,
                                              int* __restrict__ bsum, int N, int NB2) {
  const int* cnt = blockIdx.y ? cnt_s : cnt_d;
  int base = blockIdx.x * SCAN_CHUNK;
  int hi = min(N, base + SCAN_CHUNK);
  int s = 0;
  for (int i = base + threadIdx.x; i < hi; i += 256) s += cnt[i];
#pragma unroll
  for (int off = 32; off > 0; off >>= 1) s += __shfl_down(s, off);
  __shared__ int ws[4];
  if ((threadIdx.x & 63) == 0) ws[threadIdx.x >> 6] = s;
  __syncthreads();
  if (threadIdx.x == 0) bsum[blockIdx.y * NB2 + blockIdx.x] = ws[0] + ws[1] + ws[2] + ws[3];
}

__global__ void k_bscan(int* __restrict__ bsum, int NB2) {
  if (threadIdx.x < 2) {
    int* b = bsum + threadIdx.x * NB2;
    int run = 0;
    for (int i = 0; i < NB2; ++i) {
      int t = b[i];
      b[i] = run;
      run += t;
    }
  }
}

__global__ __launch_bounds__(256) void k_scanf(const int* __restrict__ cnt_d,
                                               const int* __restrict__ cnt_s,
                                               const int* __restrict__ bsum,
                                               int* __restrict__ rp_d, int* __restrict__ rp_s,
                                               int N, int NB2) {
  const int* cnt = blockIdx.y ? cnt_s : cnt_d;
  int* rp = blockIdx.y ? rp_s : rp_d;
  const int t = threadIdx.x;
  const int idx0 = blockIdx.x * SCAN_CHUNK + t * 8;
  int vals[8];
  int s = 0;
#pragma unroll
  for (int j = 0; j < 8; ++j) {
    int i = idx0 + j;
    int v = (i < N) ? cnt[i] : 0;
    vals[j] = v;
    s += v;
  }
  __shared__ int sums[256];
  sums[t] = s;
  __syncthreads();
  for (int off = 1; off < 256; off <<= 1) {
    int v = (t >= off) ? sums[t - off] : 0;
    __syncthreads();
    sums[t] += v;
    __syncthreads();
  }
  int run = bsum[blockIdx.y * NB2 + blockIdx.x] + ((t > 0) ? sums[t - 1] : 0);
#pragma unroll
  for (int j = 0; j < 8; ++j) {
    int i = idx0 + j;
    if (i < N) {
      run += vals[j];
      rp[i + 1] = run;
    }
  }
  if (t == 0 && blockIdx.x == 0) rp[0] = 0;
}

__global__ __launch_bounds__(256) void k_scatter2(
    const int* __restrict__ eidx, int E, int N,
    const int* __restrict__ partial_d, const int* __restrict__ rp_d, int* __restrict__ csr_src,
    const int* __restrict__ partial_s, const int* __restrict__ rp_s, int* __restrict__ csr_dst) {
  extern __shared__ unsigned int cur[];  // [2*nw]
  int nw = (N + 1) >> 1;
  for (int i = threadIdx.x; i < 2 * nw; i += blockDim.x) cur[i] = 0u;
  __syncthreads();
  const int* src = eidx;
  const int* dst = eidx + E;
  int chunk = (E + CSR_B - 1) / CSR_B;
  int beg = blockIdx.x * chunk, end = min(E, beg + chunk);
  for (int e = beg + threadIdx.x; e < end; e += blockDim.x) {
    int d = dst[e], s = src[e];
    int shd = (d & 1) * 16;
    unsigned int old = atomicAdd(&cur[d >> 1], 1u << shd);
    csr_src[rp_d[d] + partial_d[(size_t)blockIdx.x * N + d] + (int)((old >> shd) & 0xFFFFu)] = s;
    int shs = (s & 1) * 16;
    unsigned int old2 = atomicAdd(&cur[nw + (s >> 1)], 1u << shs);
    csr_dst[rp_s[s] + partial_s[(size_t)blockIdx.x * N + s] + (int)((old2 >> shs) & 0xFFFFu)] = d;
  }
}

// ============ weights prep ============
__global__ void k_build_w(const float* __restrict__ W_msg, const float* __restrict__ W_self,
                          const float* __restrict__ b_msg, float* __restrict__ Wcat,
                          float* __restrict__ bcat) {
  int idx = blockIdx.x * blockDim.x + threadIdx.x;  // 256*256
  int k = idx >> 8, j = idx & 255;
  Wcat[idx] = (j < 128) ? W_msg[k * 128 + j] : W_self[k * 128 + (j - 128)];
  if (idx < 256) bcat[idx] = (idx < 128) ? b_msg[idx] : 0.0f;
}

// ============ GEMM: xw[M,256] = x[M,256] @ Wcat + bcat ============
// BM=64, BN=128, BK=16, 256 thr, 4 rows x 8 cols/thread, register-prefetch
// + DOUBLE-BUFFERED LDS: one barrier per k-step (write next tile to the
// alternate buffer while current is being read).
__device__ __forceinline__ float4 enc4(float p, float sf, float4 we0, float4 we1, float4 be) {
  float4 r;
  r.x = fmaxf(fmaf(p, we0.x, fmaf(sf, we1.x, be.x)), 0.f);
  r.y = fmaxf(fmaf(p, we0.y, fmaf(sf, we1.y, be.y)), 0.f);
  r.z = fmaxf(fmaf(p, we0.z, fmaf(sf, we1.z, be.z)), 0.f);
  r.w = fmaxf(fmaf(p, we0.w, fmaf(sf, we1.w, be.w)), 0.f);
  return r;
}

template <bool IT0>
__global__ __launch_bounds__(256) void k_gemm(
    const float* __restrict__ pos, const float* __restrict__ sfeat,
    const float* __restrict__ hsrc, const float* __restrict__ W_enc,
    const float* __restrict__ b_enc, const float* __restrict__ B,
    const float* __restrict__ bias, float* __restrict__ C, int M) {
  __shared__ float As[2][16][68];    // [buf][k][row], +4 pad
  __shared__ float Bs[2][16][132];   // [buf][k][col], +4 pad
  const int m0 = blockIdx.x * 64, n0 = blockIdx.y * 128;
  const int t = threadIdx.x;
  const int ty = t >> 4;          // [0,16): rows ty*4..ty*4+3
  const int tx = t & 15;          // [0,16): cols tx*4 and 64+tx*4
  const int lr = t >> 2, lq = (t & 3) << 2;  // A-load: row [0,64), col quad
  const int row_ld = m0 + lr;
  const bool valid = row_ld < M;
  float p = 0.f, sf = 0.f;
  if (valid) { p = pos[row_ld]; sf = sfeat[row_ld]; }
  const int bk0 = t >> 5, bc0 = (t & 31) << 2;
  const int bk1 = (t + 256) >> 5, bc1 = bc0;
  const int KMAX = IT0 ? 128 : 256;

  auto loadA = [&](int k0) -> float4 {
    float4 av = make_float4(0.f, 0.f, 0.f, 0.f);
    const int col = k0 + lq;
    if (valid) {
      if (col < 128) {
        float4 we0 = *reinterpret_cast<const float4*>(&W_enc[col]);
        float4 we1 = *reinterpret_cast<const float4*>(&W_enc[128 + col]);
        float4 be = *reinterpret_cast<const float4*>(&b_enc[col]);
        av = enc4(p, sf, we0, we1, be);
      } else {
        av = *reinterpret_cast<const float4*>(&hsrc[(size_t)row_ld * 128 + col - 128]);
      }
    }
    return av;
  };

  // prologue: stage tile 0 into buffer 0
  {
    float4 ra = loadA(0);
    float4 rb0 = *reinterpret_cast<const float4*>(&B[(size_t)bk0 * 256 + n0 + bc0]);
    float4 rb1 = *reinterpret_cast<const float4*>(&B[(size_t)bk1 * 256 + n0 + bc1]);
    As[0][lq + 0][lr] = ra.x;
    As[0][lq + 1][lr] = ra.y;
    As[0][lq + 2][lr] = ra.z;
    As[0][lq + 3][lr] = ra.w;
    *reinterpret_cast<float4*>(&Bs[0][bk0][bc0]) = rb0;
    *reinterpret_cast<float4*>(&Bs[0][bk1][bc1]) = rb1;
  }
  __syncthreads();

  float acc[4][8] = {};
  for (int k0 = 0; k0 < KMAX; k0 += 16) {
    const int cur = (k0 >> 4) & 1;
    const bool more = (k0 + 16) < KMAX;
    float4 ra, rb0, rb1;
    if (more) {  // issue next tile's loads (complete under compute)
      ra = loadA(k0 + 16);
      rb0 = *reinterpret_cast<const float4*>(&B[(size_t)(k0 + 16 + bk0) * 256 + n0 + bc0]);
      rb1 = *reinterpret_cast<const float4*>(&B[(size_t)(k0 + 16 + bk1) * 256 + n0 + bc1]);
    }
#pragma unroll
    for (int k = 0; k < 16; ++k) {
      float4 a4 = *reinterpret_cast<const float4*>(&As[cur][k][ty * 4]);
      float4 b0 = *reinterpret_cast<const float4*>(&Bs[cur][k][tx * 4]);
      float4 b1 = *reinterpret_cast<const float4*>(&Bs[cur][k][64 + tx * 4]);
      const float a[4] = {a4.x, a4.y, a4.z, a4.w};
      const float bb[8] = {b0.x, b0.y, b0.z, b0.w, b1.x, b1.y, b1.z, b1.w};
#pragma unroll
      for (int i = 0; i < 4; ++i)
#pragma unroll
        for (int j = 0; j < 8; ++j) acc[i][j] = fmaf(a[i], bb[j], acc[i][j]);
    }
    if (more) {  // write next tile to the alternate buffer (no race: other buf)
      const int nxt = cur ^ 1;
      As[nxt][lq + 0][lr] = ra.x;
      As[nxt][lq + 1][lr] = ra.y;
      As[nxt][lq + 2][lr] = ra.z;
      As[nxt][lq + 3][lr] = ra.w;
      *reinterpret_cast<float4*>(&Bs[nxt][bk0][bc0]) = rb0;
      *reinterpret_cast<float4*>(&Bs[nxt][bk1][bc1]) = rb1;
    }
    __syncthreads();  // the only barrier per step
  }
  float4 bi0 = *reinterpret_cast<const float4*>(&bias[n0 + tx * 4]);
  float4 bi1 = *reinterpret_cast<const float4*>(&bias[n0 + 64 + tx * 4]);
#pragma unroll
  for (int i = 0; i < 4; ++i) {
    int row = m0 + ty * 4 + i;
    if (row < M) {
      float4 o0 = make_float4(acc[i][0] + bi0.x, acc[i][1] + bi0.y, acc[i][2] + bi0.z,
                              acc[i][3] + bi0.w);
      float4 o1 = make_float4(acc[i][4] + bi1.x, acc[i][5] + bi1.y, acc[i][6] + bi1.z,
                              acc[i][7] + bi1.w);
      *reinterpret_cast<float4*>(&C[(size_t)row * 256 + n0 + tx * 4]) = o0;
      *reinterpret_cast<float4*>(&C[(size_t)row * 256 + n0 + 64 + tx * 4]) = o1;
    }
  }
}

// ============ aggmax: feature-chunked for per-XCD L2 residence ============
__global__ __launch_bounds__(256) void k_aggmax(
    const float* __restrict__ xw, const int* __restrict__ row_ptr,
    const int* __restrict__ csr_src, float* __restrict__ agg, int N, int Nh) {
  const int cx = blockIdx.x & 7;
  const int chunk = cx & 3;
  const int half = cx >> 2;
  const int hw = threadIdx.x >> 5;
  const int sub = threadIdx.x & 31;
  const int node = half * Nh + blockIdx.y * 8 + hw;
  const int hi = half ? N : Nh;
  if (node >= hi) return;
  const float* base = xw + chunk * 32 + sub;
  const int beg = row_ptr[node], end = row_ptr[node + 1];
  float m0 = 0.f, m1 = 0.f, m2 = 0.f, m3 = 0.f;
  int i = beg;
  for (; i + 3 < end; i += 4) {
    int e0 = csr_src[i], e1 = csr_src[i + 1], e2 = csr_src[i + 2], e3 = csr_src[i + 3];
    float f0 = base[(size_t)e0 * 256];
    float f1 = base[(size_t)e1 * 256];
    float f2 = base[(size_t)e2 * 256];
    float f3 = base[(size_t)e3 * 256];
    m0 = fmaxf(m0, f0); m1 = fmaxf(m1, f1);
    m2 = fmaxf(m2, f2); m3 = fmaxf(m3, f3);
  }
  for (; i < end; ++i) m0 = fmaxf(m0, base[(size_t)csr_src[i] * 256]);
  m0 = fmaxf(fmaxf(m0, m1), fmaxf(m2, m3));
  agg[(size_t)node * 128 + chunk * 32 + sub] = m0;
}

// ============ update GEMM: h = relu(agg@W_agg + self + b_upd); fused u,v ============
__global__ __launch_bounds__(256) void k_update2(
    const float* __restrict__ agg, const float* __restrict__ W_agg,
    const float* __restrict__ b_upd, const float* __restrict__ xw,
    const float* __restrict__ W_dec, const float* __restrict__ b_dec,
    float* __restrict__ h, float* __restrict__ u, float* __restrict__ v, int M) {
  __shared__ float AsT[32][33];
  __shared__ float Bs[32][128];
  const int m0 = blockIdx.x * 32;
  const int t = threadIdx.x;
  const int ty = t >> 5, tx = t & 31;
  const int lar = t >> 3, lac = (t & 7) << 2;
  float acc[4][4] = {};
  for (int k0 = 0; k0 < 128; k0 += 32) {
    {
      float4 av = make_float4(0.f, 0.f, 0.f, 0.f);
      int row = m0 + lar;
      if (row < M) av = *reinterpret_cast<const float4*>(&agg[(size_t)row * 128 + k0 + lac]);
      AsT[lac + 0][lar] = av.x;
      AsT[lac + 1][lar] = av.y;
      AsT[lac + 2][lar] = av.z;
      AsT[lac + 3][lar] = av.w;
#pragma unroll
      for (int p = 0; p < 4; ++p) {
        int br = (t >> 5) + p * 8;
        *reinterpret_cast<float4*>(&Bs[br][tx * 4]) =
            *reinterpret_cast<const float4*>(&W_agg[(size_t)(k0 + br) * 128 + tx * 4]);
      }
    }
    __syncthreads();
#pragma unroll
    for (int k = 0; k < 32; ++k) {
      float4 a4 = *reinterpret_cast<const float4*>(&AsT[k][ty * 4]);
      float4 b4 = *reinterpret_cast<const float4*>(&Bs[k][tx * 4]);
      const float aa[4] = {a4.x, a4.y, a4.z, a4.w};
      const float bb[4] = {b4.x, b4.y, b4.z, b4.w};
#pragma unroll
      for (int j = 0; j < 4; ++j)
#pragma unroll
        for (int c = 0; c < 4; ++c) acc[j][c] = fmaf(aa[j], bb[c], acc[j][c]);
    }
    __syncthreads();
  }
  const float4 bu4 = *reinterpret_cast<const float4*>(&b_upd[tx * 4]);
  const float4 wdu = *reinterpret_cast<const float4*>(&W_dec[tx * 4]);
  const float4 wdv = *reinterpret_cast<const float4*>(&W_dec[128 + tx * 4]);
  const float bd = b_dec[0];
#pragma unroll
  for (int j = 0; j < 4; ++j) {
    int row = m0 + ty * 4 + j;
    if (row >= M) continue;
    float4 sf = *reinterpret_cast<const float4*>(&xw[(size_t)row * 256 + 128 + tx * 4]);
    float4 h4;
    h4.x = fmaxf(acc[j][0] + sf.x + bu4.x, 0.f);
    h4.y = fmaxf(acc[j][1] + sf.y + bu4.y, 0.f);
    h4.z = fmaxf(acc[j][2] + sf.z + bu4.z, 0.f);
    h4.w = fmaxf(acc[j][3] + sf.w + bu4.w, 0.f);
    *reinterpret_cast<float4*>(&h[(size_t)row * 128 + tx * 4]) = h4;
    float up = h4.x * wdu.x + h4.y * wdu.y + h4.z * wdu.z + h4.w * wdu.w;
    float vp = h4.x * wdv.x + h4.y * wdv.y + h4.z * wdv.z + h4.w * wdv.w;
#pragma unroll
    for (int m = 16; m > 0; m >>= 1) {
      up += __shfl_xor(up, m);
      vp += __shfl_xor(vp, m);
    }
    if (tx == 0) {
      u[row] = up + bd;
      v[row] = vp;
    }
  }
}

// ============ fused losses: edge BCE partials + node y/max + y-BCE partials ============
#define GB 512
__global__ __launch_bounds__(256) void k_losses(
    const int* __restrict__ src, const int* __restrict__ dst, const float* __restrict__ u,
    const float* __restrict__ v, const int* __restrict__ tgt, const int* __restrict__ row_ptr,
    const int* __restrict__ csr_src, const int* __restrict__ row_ptr2,
    const int* __restrict__ csr_dst, const int* __restrict__ reach_row,
    float* __restrict__ ybuf, float* __restrict__ yout, int write_out,
    double* __restrict__ pe_slot, double* __restrict__ py_slot, int E, int N) {
  __shared__ double wsum[4];
  double term = 0.0;
  for (int e = blockIdx.x * blockDim.x + threadIdx.x; e < E; e += GB * 256) {
    float l = u[src[e]] + v[dst[e]];
    float xsel = (tgt[e] != 0) ? -l : l;
    float sp = log1pf(expf(xsel));
    term += (double)fmaxf(-sp, -100.0f);
  }
#pragma unroll
  for (int off = 32; off > 0; off >>= 1) term += __shfl_down(term, off);
  if ((threadIdx.x & 63) == 0) wsum[threadIdx.x >> 6] = term;
  __syncthreads();
  if (threadIdx.x == 0) pe_slot[blockIdx.x] = wsum[0] + wsum[1] + wsum[2] + wsum[3];
  __syncthreads();
  double c = 0.0;
  for (int n = blockIdx.x * blockDim.x + threadIdx.x; n < N; n += GB * 256) {
    float mu = -INFINITY, mv = -INFINITY;
    const int b1 = row_ptr[n], e1 = row_ptr[n + 1];
    for (int i = b1; i < e1; ++i) mu = fmaxf(mu, u[csr_src[i]]);
    const int b2 = row_ptr2[n], e2 = row_ptr2[n + 1];
    for (int i = b2; i < e2; ++i) mv = fmaxf(mv, v[csr_dst[i]]);
    float m = fmaxf(mu + v[n], u[n] + mv);
    float a = 1.0f / (1.0f + expf(-m));
    float yv = (a >= 0.8f) ? 1.0f : 0.0f;
    ybuf[n] = yv;
    if (write_out) yout[n] = yv;
    if ((float)reach_row[n] != yv) c = 100.0;
  }
#pragma unroll
  for (int off = 32; off > 0; off >>= 1) c += __shfl_down(c, off);
  if ((threadIdx.x & 63) == 0) wsum[threadIdx.x >> 6] = c;
  __syncthreads();
  if (threadIdx.x == 0) py_slot[blockIdx.x] = wsum[0] + wsum[1] + wsum[2] + wsum[3];
}

__global__ void k_final(const double* __restrict__ pe, const double* __restrict__ py,
                        float* __restrict__ out4, int N, int E, int T) {
  __shared__ double le[8], ly[8];
  int lane = threadIdx.x;  // 64 threads
  for (int it = 0; it < T; ++it) {
    double s = 0.0;
    for (int i = lane; i < GB; i += 64) s += pe[(size_t)it * GB + i];
#pragma unroll
    for (int off = 32; off > 0; off >>= 1) s += __shfl_down(s, off);
    if (lane == 0) le[it] = s;
    double s2 = 0.0;
    for (int i = lane; i < GB; i += 64) s2 += py[(size_t)it * GB + i];
#pragma unroll
    for (int off = 32; off > 0; off >>= 1) s2 += __shfl_down(s2, off);
    if (lane == 0) ly[it] = s2;
  }
  __syncthreads();
  if (lane == 0) {
    float loss_x = (float)(-le[T - 1] / (double)E);
    float loss_h = 0.0f;
    for (int i = 0; i < T - 1; ++i) loss_h += (float)(-le[i] / (double)E);
    float yl_x = (float)(ly[T - 1] / (double)N);
    float yl_h = 0.0f;
    for (int i = 0; i < T - 1; ++i) yl_h += (float)(ly[i] / (double)N);
    out4[0] = loss_x;
    out4[1] = loss_h;
    out4[2] = yl_x;
    out4[3] = yl_h;
  }
}

// ============ launch ============
extern "C" void kernel_launch(void* const* d_in, const int* in_sizes, int n_in,
                              void* d_out, int out_size, void* d_ws, size_t ws_size,
                              hipStream_t stream) {
  const float* pos = (const float*)d_in[0];
  const float* s = (const float*)d_in[1];
  const int* eidx = (const int*)d_in[2];
  const int* pi = (const int*)d_in[3];
  const int* pi_h = (const int*)d_in[4];
  const int* reach = (const int*)d_in[5];
  const float* W_enc = (const float*)d_in[6];
  const float* b_enc = (const float*)d_in[7];
  const float* W_msg = (const float*)d_in[8];
  const float* b_msg = (const float*)d_in[9];
  const float* W_self = (const float*)d_in[10];
  const float* W_agg = (const float*)d_in[11];
  const float* b_upd = (const float*)d_in[12];
  const float* W_dec = (const float*)d_in[13];
  const float* b_dec = (const float*)d_in[14];

  const int N = in_sizes[0];
  const int E = in_sizes[3];
  const int T = in_sizes[4] / in_sizes[3];
  const int* src = eidx;
  const int* dst = eidx + E;

  char* w = (char*)d_ws;
  auto alloc = [&](size_t bytes) {
    char* p = w;
    w += (bytes + 255) & ~(size_t)255;
    return p;
  };
  float* xw = (float*)alloc((size_t)N * 256 * 4);
  float* agg = (float*)alloc((size_t)N * 128 * 4);
  float* h = (float*)alloc((size_t)N * 128 * 4);
  float* Wcat = (float*)alloc(256 * 256 * 4);
  float* bcat = (float*)alloc(256 * 4);
  float* u = (float*)alloc((size_t)N * 4);
  float* v = (float*)alloc((size_t)N * 4);
  float* ybuf = (float*)alloc((size_t)N * 4);
  int* cnt_d = (int*)alloc((size_t)N * 4);
  int* cnt_s = (int*)alloc((size_t)N * 4);
  int* row_ptr = (int*)alloc((size_t)(N + 1) * 4);
  int* row_ptr2 = (int*)alloc((size_t)(N + 1) * 4);
  int* csr_src = (int*)alloc((size_t)E * 4);
  int* csr_dst = (int*)alloc((size_t)E * 4);
  int* partial_d = (int*)alloc((size_t)CSR_B * N * 4);
  int* partial_s = (int*)alloc((size_t)CSR_B * N * 4);
  double* pe = (double*)alloc((size_t)T * GB * 8);
  double* py = (double*)alloc((size_t)T * GB * 8);
  const int NB2 = (N + SCAN_CHUNK - 1) / SCAN_CHUNK;
  int* bsum = (int*)alloc((size_t)2 * NB2 * 4);

  float* outy = (float*)d_out;
  float* out4 = outy + N;

  k_build_w<<<256, 256, 0, stream>>>(W_msg, W_self, b_msg, Wcat, bcat);

  const size_t lds2 = (size_t)2 * ((N + 1) >> 1) * 4;  // ~80 KB
  k_hist2<<<CSR_B, 256, lds2, stream>>>(eidx, E, N, partial_d, partial_s);
  k_colscan2<<<(2 * N + 255) / 256, 256, 0, stream>>>(partial_d, cnt_d, partial_s, cnt_s, N);
  k_bsum<<<dim3(NB2, 2), 256, 0, stream>>>(cnt_d, cnt_s, bsum, N, NB2);
  k_bscan<<<1, 64, 0, stream>>>(bsum, NB2);
  k_scanf<<<dim3(NB2, 2), 256, 0, stream>>>(cnt_d, cnt_s, bsum, row_ptr, row_ptr2, N, NB2);
  k_scatter2<<<CSR_B, 256, lds2, stream>>>(eidx, E, N, partial_d, row_ptr, csr_src, partial_s,
                                           row_ptr2, csr_dst);

  const int Nh = (N + 1) / 2;
  const int NB = (Nh + 7) / 8;

  const float* sfeat = s;
  for (int it = 0; it < T; ++it) {
    dim3 g1((N + 63) / 64, 2);
    if (it == 0)
      k_gemm<true><<<g1, 256, 0, stream>>>(pos, sfeat, h, W_enc, b_enc, Wcat, bcat, xw, N);
    else
      k_gemm<false><<<g1, 256, 0, stream>>>(pos, sfeat, h, W_enc, b_enc, Wcat, bcat, xw, N);

    k_aggmax<<<dim3(8, NB), 256, 0, stream>>>(xw, row_ptr, csr_src, agg, N, Nh);

    k_update2<<<(N + 31) / 32, 256, 0, stream>>>(agg, W_agg, b_upd, xw, W_dec, b_dec,
                                                 h, u, v, N);

    const int* tgt = (it < T - 1) ? (pi_h + (size_t)(it + 1) * E) : pi;
    const int* rrow = (it < T - 1) ? (reach + (size_t)(it + 1) * N) : (reach + (size_t)(T - 1) * N);
    k_losses<<<GB, 256, 0, stream>>>(src, dst, u, v, tgt, row_ptr, csr_src, row_ptr2, csr_dst,
                                     rrow, ybuf, outy, (it == T - 1) ? 1 : 0,
                                     pe + (size_t)it * GB, py + (size_t)it * GB, E, N);
    sfeat = ybuf;
  }
  k_final<<<1, 64, 0, stream>>>(pe, py, out4, N, E, T);
}

// Round 18
// 493.166 us; speedup vs baseline: 1.0579x; 1.0579x over previous
//
#include <hip/hip_runtime.h>

// ============ CSR build (both directions, one pass, no global atomics) ============
#define CSR_B 128

__global__ __launch_bounds__(256) void k_hist2(const int* __restrict__ eidx, int E, int N,
                                               int* __restrict__ partial_d,
                                               int* __restrict__ partial_s) {
  extern __shared__ unsigned int hist[];  // [2*nw]
  int nw = (N + 1) >> 1;
  for (int i = threadIdx.x; i < 2 * nw; i += blockDim.x) hist[i] = 0u;
  __syncthreads();
  const int* src = eidx;
  const int* dst = eidx + E;
  int chunk = (E + CSR_B - 1) / CSR_B;
  int beg = blockIdx.x * chunk, end = min(E, beg + chunk);
  for (int e = beg + threadIdx.x; e < end; e += blockDim.x) {
    int d = dst[e];
    atomicAdd(&hist[d >> 1], 1u << ((d & 1) * 16));
    int s = src[e];
    atomicAdd(&hist[nw + (s >> 1)], 1u << ((s & 1) * 16));
  }
  __syncthreads();
  for (int i = threadIdx.x; i < N; i += blockDim.x) {
    partial_d[(size_t)blockIdx.x * N + i] = (int)((hist[i >> 1] >> ((i & 1) * 16)) & 0xFFFFu);
    partial_s[(size_t)blockIdx.x * N + i] = (int)((hist[nw + (i >> 1)] >> ((i & 1) * 16)) & 0xFFFFu);
  }
}

__global__ __launch_bounds__(256) void k_colscan2(int* __restrict__ partial_d,
                                                  int* __restrict__ cnt_d,
                                                  int* __restrict__ partial_s,
                                                  int* __restrict__ cnt_s, int N) {
  int g = blockIdx.x * blockDim.x + threadIdx.x;
  int* partial;
  int* cnt;
  int bin;
  if (g < N) { partial = partial_d; cnt = cnt_d; bin = g; }
  else if (g < 2 * N) { partial = partial_s; cnt = cnt_s; bin = g - N; }
  else return;
  int run = 0;
  for (int b = 0; b < CSR_B; ++b) {
    int t = partial[(size_t)b * N + bin];
    partial[(size_t)b * N + bin] = run;
    run += t;
  }
  cnt[bin] = run;
}

// ============ hierarchical scan ============
#define SCAN_CHUNK 2048

__global__ __launch_bounds__(256) void k_bsum(const int* __restrict__ cnt_d,
                                              const int* __restrict__ cnt_s,
                                              int* __restrict__ bsum, int N, int NB2) {
  const int* cnt = blockIdx.y ? cnt_s : cnt_d;
  int base = blockIdx.x * SCAN_CHUNK;
  int hi = min(N, base + SCAN_CHUNK);
  int s = 0;
  for (int i = base + threadIdx.x; i < hi; i += 256) s += cnt[i];
#pragma unroll
  for (int off = 32; off > 0; off >>= 1) s += __shfl_down(s, off);
  __shared__ int ws[4];
  if ((threadIdx.x & 63) == 0) ws[threadIdx.x >> 6] = s;
  __syncthreads();
  if (threadIdx.x == 0) bsum[blockIdx.y * NB2 + blockIdx.x] = ws[0] + ws[1] + ws[2] + ws[3];
}

__global__ void k_bscan(int* __restrict__ bsum, int NB2) {
  if (threadIdx.x < 2) {
    int* b = bsum + threadIdx.x * NB2;
    int run = 0;
    for (int i = 0; i < NB2; ++i) {
      int t = b[i];
      b[i] = run;
      run += t;
    }
  }
}

__global__ __launch_bounds__(256) void k_scanf(const int* __restrict__ cnt_d,
                                               const int* __restrict__ cnt_s,
                                               const int* __restrict__ bsum,
                                               int* __restrict__ rp_d, int* __restrict__ rp_s,
                                               int N, int NB2) {
  const int* cnt = blockIdx.y ? cnt_s : cnt_d;
  int* rp = blockIdx.y ? rp_s : rp_d;
  const int t = threadIdx.x;
  const int idx0 = blockIdx.x * SCAN_CHUNK + t * 8;
  int vals[8];
  int s = 0;
#pragma unroll
  for (int j = 0; j < 8; ++j) {
    int i = idx0 + j;
    int v = (i < N) ? cnt[i] : 0;
    vals[j] = v;
    s += v;
  }
  __shared__ int sums[256];
  sums[t] = s;
  __syncthreads();
  for (int off = 1; off < 256; off <<= 1) {
    int v = (t >= off) ? sums[t - off] : 0;
    __syncthreads();
    sums[t] += v;
    __syncthreads();
  }
  int run = bsum[blockIdx.y * NB2 + blockIdx.x] + ((t > 0) ? sums[t - 1] : 0);
#pragma unroll
  for (int j = 0; j < 8; ++j) {
    int i = idx0 + j;
    if (i < N) {
      run += vals[j];
      rp[i + 1] = run;
    }
  }
  if (t == 0 && blockIdx.x == 0) rp[0] = 0;
}

__global__ __launch_bounds__(256) void k_scatter2(
    const int* __restrict__ eidx, int E, int N,
    const int* __restrict__ partial_d, const int* __restrict__ rp_d, int* __restrict__ csr_src,
    const int* __restrict__ partial_s, const int* __restrict__ rp_s, int* __restrict__ csr_dst) {
  extern __shared__ unsigned int cur[];  // [2*nw]
  int nw = (N + 1) >> 1;
  for (int i = threadIdx.x; i < 2 * nw; i += blockDim.x) cur[i] = 0u;
  __syncthreads();
  const int* src = eidx;
  const int* dst = eidx + E;
  int chunk = (E + CSR_B - 1) / CSR_B;
  int beg = blockIdx.x * chunk, end = min(E, beg + chunk);
  for (int e = beg + threadIdx.x; e < end; e += blockDim.x) {
    int d = dst[e], s = src[e];
    int shd = (d & 1) * 16;
    unsigned int old = atomicAdd(&cur[d >> 1], 1u << shd);
    csr_src[rp_d[d] + partial_d[(size_t)blockIdx.x * N + d] + (int)((old >> shd) & 0xFFFFu)] = s;
    int shs = (s & 1) * 16;
    unsigned int old2 = atomicAdd(&cur[nw + (s >> 1)], 1u << shs);
    csr_dst[rp_s[s] + partial_s[(size_t)blockIdx.x * N + s] + (int)((old2 >> shs) & 0xFFFFu)] = d;
  }
}

// ============ weights prep ============
__global__ void k_build_w(const float* __restrict__ W_msg, const float* __restrict__ W_self,
                          const float* __restrict__ b_msg, float* __restrict__ Wcat,
                          float* __restrict__ bcat) {
  int idx = blockIdx.x * blockDim.x + threadIdx.x;  // 256*256
  int k = idx >> 8, j = idx & 255;
  Wcat[idx] = (j < 128) ? W_msg[k * 128 + j] : W_self[k * 128 + (j - 128)];
  if (idx < 256) bcat[idx] = (idx < 128) ? b_msg[idx] : 0.0f;
}

// ============ GEMM: xw[M,256] = x[M,256] @ Wcat + bcat ============
// BM=64, BN=128, BK=16, 256 thr, 4 rows x 8 cols/thread + register-prefetch
// (commit regs->LDS, barrier, issue next loads, compute, barrier).
// NOTE: single-buffered on purpose — explicit LDS dbuf raises VGPR 48->128
// and regresses (measured twice, R4/R15).
__device__ __forceinline__ float4 enc4(float p, float sf, float4 we0, float4 we1, float4 be) {
  float4 r;
  r.x = fmaxf(fmaf(p, we0.x, fmaf(sf, we1.x, be.x)), 0.f);
  r.y = fmaxf(fmaf(p, we0.y, fmaf(sf, we1.y, be.y)), 0.f);
  r.z = fmaxf(fmaf(p, we0.z, fmaf(sf, we1.z, be.z)), 0.f);
  r.w = fmaxf(fmaf(p, we0.w, fmaf(sf, we1.w, be.w)), 0.f);
  return r;
}

template <bool IT0>
__global__ __launch_bounds__(256) void k_gemm(
    const float* __restrict__ pos, const float* __restrict__ sfeat,
    const float* __restrict__ hsrc, const float* __restrict__ W_enc,
    const float* __restrict__ b_enc, const float* __restrict__ B,
    const float* __restrict__ bias, float* __restrict__ C, int M) {
  __shared__ float As[16][68];    // [k][row], +4 pad
  __shared__ float Bs[16][132];   // [k][col], +4 pad
  const int m0 = blockIdx.x * 64, n0 = blockIdx.y * 128;
  const int t = threadIdx.x;
  const int ty = t >> 4;          // [0,16): rows ty*4..ty*4+3
  const int tx = t & 15;          // [0,16): cols tx*4 and 64+tx*4
  const int lr = t >> 2, lq = (t & 3) << 2;  // A-load: row [0,64), col quad
  const int row_ld = m0 + lr;
  const bool valid = row_ld < M;
  float p = 0.f, sf = 0.f;
  if (valid) { p = pos[row_ld]; sf = sfeat[row_ld]; }
  const int bk0 = t >> 5, bc0 = (t & 31) << 2;
  const int bk1 = (t + 256) >> 5, bc1 = bc0;
  const int KMAX = IT0 ? 128 : 256;

  auto loadA = [&](int k0) -> float4 {
    float4 av = make_float4(0.f, 0.f, 0.f, 0.f);
    const int col = k0 + lq;
    if (valid) {
      if (col < 128) {
        float4 we0 = *reinterpret_cast<const float4*>(&W_enc[col]);
        float4 we1 = *reinterpret_cast<const float4*>(&W_enc[128 + col]);
        float4 be = *reinterpret_cast<const float4*>(&b_enc[col]);
        av = enc4(p, sf, we0, we1, be);
      } else {
        av = *reinterpret_cast<const float4*>(&hsrc[(size_t)row_ld * 128 + col - 128]);
      }
    }
    return av;
  };

  float4 ra = loadA(0);
  float4 rb0 = *reinterpret_cast<const float4*>(&B[(size_t)bk0 * 256 + n0 + bc0]);
  float4 rb1 = *reinterpret_cast<const float4*>(&B[(size_t)bk1 * 256 + n0 + bc1]);

  float acc[4][8] = {};
  for (int k0 = 0; k0 < KMAX; k0 += 16) {
    As[lq + 0][lr] = ra.x;
    As[lq + 1][lr] = ra.y;
    As[lq + 2][lr] = ra.z;
    As[lq + 3][lr] = ra.w;
    *reinterpret_cast<float4*>(&Bs[bk0][bc0]) = rb0;
    *reinterpret_cast<float4*>(&Bs[bk1][bc1]) = rb1;
    __syncthreads();
    const bool more = (k0 + 16) < KMAX;
    if (more) {
      ra = loadA(k0 + 16);
      rb0 = *reinterpret_cast<const float4*>(&B[(size_t)(k0 + 16 + bk0) * 256 + n0 + bc0]);
      rb1 = *reinterpret_cast<const float4*>(&B[(size_t)(k0 + 16 + bk1) * 256 + n0 + bc1]);
    }
#pragma unroll
    for (int k = 0; k < 16; ++k) {
      float4 a4 = *reinterpret_cast<const float4*>(&As[k][ty * 4]);
      float4 b0 = *reinterpret_cast<const float4*>(&Bs[k][tx * 4]);
      float4 b1 = *reinterpret_cast<const float4*>(&Bs[k][64 + tx * 4]);
      const float a[4] = {a4.x, a4.y, a4.z, a4.w};
      const float bb[8] = {b0.x, b0.y, b0.z, b0.w, b1.x, b1.y, b1.z, b1.w};
#pragma unroll
      for (int i = 0; i < 4; ++i)
#pragma unroll
        for (int j = 0; j < 8; ++j) acc[i][j] = fmaf(a[i], bb[j], acc[i][j]);
    }
    __syncthreads();
  }
  float4 bi0 = *reinterpret_cast<const float4*>(&bias[n0 + tx * 4]);
  float4 bi1 = *reinterpret_cast<const float4*>(&bias[n0 + 64 + tx * 4]);
#pragma unroll
  for (int i = 0; i < 4; ++i) {
    int row = m0 + ty * 4 + i;
    if (row < M) {
      float4 o0 = make_float4(acc[i][0] + bi0.x, acc[i][1] + bi0.y, acc[i][2] + bi0.z,
                              acc[i][3] + bi0.w);
      float4 o1 = make_float4(acc[i][4] + bi1.x, acc[i][5] + bi1.y, acc[i][6] + bi1.z,
                              acc[i][7] + bi1.w);
      *reinterpret_cast<float4*>(&C[(size_t)row * 256 + n0 + tx * 4]) = o0;
      *reinterpret_cast<float4*>(&C[(size_t)row * 256 + n0 + 64 + tx * 4]) = o1;
    }
  }
}

// ============ aggmax: feature-chunked for per-XCD L2 residence, 8-deep MLP ============
__global__ __launch_bounds__(256) void k_aggmax(
    const float* __restrict__ xw, const int* __restrict__ row_ptr,
    const int* __restrict__ csr_src, float* __restrict__ agg, int N, int Nh) {
  const int cx = blockIdx.x & 7;
  const int chunk = cx & 3;
  const int half = cx >> 2;
  const int hw = threadIdx.x >> 5;
  const int sub = threadIdx.x & 31;
  const int node = half * Nh + blockIdx.y * 8 + hw;
  const int hi = half ? N : Nh;
  if (node >= hi) return;
  const float* base = xw + chunk * 32 + sub;
  const int beg = row_ptr[node], end = row_ptr[node + 1];
  float m0 = 0.f, m1 = 0.f, m2 = 0.f, m3 = 0.f;
  float m4 = 0.f, m5 = 0.f, m6 = 0.f, m7 = 0.f;
  int i = beg;
  for (; i + 7 < end; i += 8) {  // 8 independent gathers in flight
    int e0 = csr_src[i + 0], e1 = csr_src[i + 1], e2 = csr_src[i + 2], e3 = csr_src[i + 3];
    int e4 = csr_src[i + 4], e5 = csr_src[i + 5], e6 = csr_src[i + 6], e7 = csr_src[i + 7];
    float f0 = base[(size_t)e0 * 256];
    float f1 = base[(size_t)e1 * 256];
    float f2 = base[(size_t)e2 * 256];
    float f3 = base[(size_t)e3 * 256];
    float f4 = base[(size_t)e4 * 256];
    float f5 = base[(size_t)e5 * 256];
    float f6 = base[(size_t)e6 * 256];
    float f7 = base[(size_t)e7 * 256];
    m0 = fmaxf(m0, f0); m1 = fmaxf(m1, f1);
    m2 = fmaxf(m2, f2); m3 = fmaxf(m3, f3);
    m4 = fmaxf(m4, f4); m5 = fmaxf(m5, f5);
    m6 = fmaxf(m6, f6); m7 = fmaxf(m7, f7);
  }
  for (; i < end; ++i) m0 = fmaxf(m0, base[(size_t)csr_src[i] * 256]);
  m0 = fmaxf(fmaxf(fmaxf(m0, m1), fmaxf(m2, m3)),
             fmaxf(fmaxf(m4, m5), fmaxf(m6, m7)));
  agg[(size_t)node * 128 + chunk * 32 + sub] = m0;
}

// ============ update GEMM: h = relu(agg@W_agg + self + b_upd); fused u,v ============
__global__ __launch_bounds__(256) void k_update2(
    const float* __restrict__ agg, const float* __restrict__ W_agg,
    const float* __restrict__ b_upd, const float* __restrict__ xw,
    const float* __restrict__ W_dec, const float* __restrict__ b_dec,
    float* __restrict__ h, float* __restrict__ u, float* __restrict__ v, int M) {
  __shared__ float AsT[32][33];
  __shared__ float Bs[32][128];
  const int m0 = blockIdx.x * 32;
  const int t = threadIdx.x;
  const int ty = t >> 5, tx = t & 31;
  const int lar = t >> 3, lac = (t & 7) << 2;
  float acc[4][4] = {};
  for (int k0 = 0; k0 < 128; k0 += 32) {
    {
      float4 av = make_float4(0.f, 0.f, 0.f, 0.f);
      int row = m0 + lar;
      if (row < M) av = *reinterpret_cast<const float4*>(&agg[(size_t)row * 128 + k0 + lac]);
      AsT[lac + 0][lar] = av.x;
      AsT[lac + 1][lar] = av.y;
      AsT[lac + 2][lar] = av.z;
      AsT[lac + 3][lar] = av.w;
#pragma unroll
      for (int p = 0; p < 4; ++p) {
        int br = (t >> 5) + p * 8;
        *reinterpret_cast<float4*>(&Bs[br][tx * 4]) =
            *reinterpret_cast<const float4*>(&W_agg[(size_t)(k0 + br) * 128 + tx * 4]);
      }
    }
    __syncthreads();
#pragma unroll
    for (int k = 0; k < 32; ++k) {
      float4 a4 = *reinterpret_cast<const float4*>(&AsT[k][ty * 4]);
      float4 b4 = *reinterpret_cast<const float4*>(&Bs[k][tx * 4]);
      const float aa[4] = {a4.x, a4.y, a4.z, a4.w};
      const float bb[4] = {b4.x, b4.y, b4.z, b4.w};
#pragma unroll
      for (int j = 0; j < 4; ++j)
#pragma unroll
        for (int c = 0; c < 4; ++c) acc[j][c] = fmaf(aa[j], bb[c], acc[j][c]);
    }
    __syncthreads();
  }
  const float4 bu4 = *reinterpret_cast<const float4*>(&b_upd[tx * 4]);
  const float4 wdu = *reinterpret_cast<const float4*>(&W_dec[tx * 4]);
  const float4 wdv = *reinterpret_cast<const float4*>(&W_dec[128 + tx * 4]);
  const float bd = b_dec[0];
#pragma unroll
  for (int j = 0; j < 4; ++j) {
    int row = m0 + ty * 4 + j;
    if (row >= M) continue;
    float4 sf = *reinterpret_cast<const float4*>(&xw[(size_t)row * 256 + 128 + tx * 4]);
    float4 h4;
    h4.x = fmaxf(acc[j][0] + sf.x + bu4.x, 0.f);
    h4.y = fmaxf(acc[j][1] + sf.y + bu4.y, 0.f);
    h4.z = fmaxf(acc[j][2] + sf.z + bu4.z, 0.f);
    h4.w = fmaxf(acc[j][3] + sf.w + bu4.w, 0.f);
    *reinterpret_cast<float4*>(&h[(size_t)row * 128 + tx * 4]) = h4;
    float up = h4.x * wdu.x + h4.y * wdu.y + h4.z * wdu.z + h4.w * wdu.w;
    float vp = h4.x * wdv.x + h4.y * wdv.y + h4.z * wdv.z + h4.w * wdv.w;
#pragma unroll
    for (int m = 16; m > 0; m >>= 1) {
      up += __shfl_xor(up, m);
      vp += __shfl_xor(vp, m);
    }
    if (tx == 0) {
      u[row] = up + bd;
      v[row] = vp;
    }
  }
}

// ============ fused losses: edge BCE partials + node y/max + y-BCE partials ============
#define GB 512
__global__ __launch_bounds__(256) void k_losses(
    const int* __restrict__ src, const int* __restrict__ dst, const float* __restrict__ u,
    const float* __restrict__ v, const int* __restrict__ tgt, const int* __restrict__ row_ptr,
    const int* __restrict__ csr_src, const int* __restrict__ row_ptr2,
    const int* __restrict__ csr_dst, const int* __restrict__ reach_row,
    float* __restrict__ ybuf, float* __restrict__ yout, int write_out,
    double* __restrict__ pe_slot, double* __restrict__ py_slot, int E, int N) {
  __shared__ double wsum[4];
  double term = 0.0;
  for (int e = blockIdx.x * blockDim.x + threadIdx.x; e < E; e += GB * 256) {
    float l = u[src[e]] + v[dst[e]];
    float xsel = (tgt[e] != 0) ? -l : l;
    float sp = log1pf(expf(xsel));
    term += (double)fmaxf(-sp, -100.0f);
  }
#pragma unroll
  for (int off = 32; off > 0; off >>= 1) term += __shfl_down(term, off);
  if ((threadIdx.x & 63) == 0) wsum[threadIdx.x >> 6] = term;
  __syncthreads();
  if (threadIdx.x == 0) pe_slot[blockIdx.x] = wsum[0] + wsum[1] + wsum[2] + wsum[3];
  __syncthreads();
  double c = 0.0;
  for (int n = blockIdx.x * blockDim.x + threadIdx.x; n < N; n += GB * 256) {
    float mu = -INFINITY, mv = -INFINITY;
    const int b1 = row_ptr[n], e1 = row_ptr[n + 1];
    for (int i = b1; i < e1; ++i) mu = fmaxf(mu, u[csr_src[i]]);
    const int b2 = row_ptr2[n], e2 = row_ptr2[n + 1];
    for (int i = b2; i < e2; ++i) mv = fmaxf(mv, v[csr_dst[i]]);
    float m = fmaxf(mu + v[n], u[n] + mv);
    float a = 1.0f / (1.0f + expf(-m));
    float yv = (a >= 0.8f) ? 1.0f : 0.0f;
    ybuf[n] = yv;
    if (write_out) yout[n] = yv;
    if ((float)reach_row[n] != yv) c = 100.0;
  }
#pragma unroll
  for (int off = 32; off > 0; off >>= 1) c += __shfl_down(c, off);
  if ((threadIdx.x & 63) == 0) wsum[threadIdx.x >> 6] = c;
  __syncthreads();
  if (threadIdx.x == 0) py_slot[blockIdx.x] = wsum[0] + wsum[1] + wsum[2] + wsum[3];
}

__global__ void k_final(const double* __restrict__ pe, const double* __restrict__ py,
                        float* __restrict__ out4, int N, int E, int T) {
  __shared__ double le[8], ly[8];
  int lane = threadIdx.x;  // 64 threads
  for (int it = 0; it < T; ++it) {
    double s = 0.0;
    for (int i = lane; i < GB; i += 64) s += pe[(size_t)it * GB + i];
#pragma unroll
    for (int off = 32; off > 0; off >>= 1) s += __shfl_down(s, off);
    if (lane == 0) le[it] = s;
    double s2 = 0.0;
    for (int i = lane; i < GB; i += 64) s2 += py[(size_t)it * GB + i];
#pragma unroll
    for (int off = 32; off > 0; off >>= 1) s2 += __shfl_down(s2, off);
    if (lane == 0) ly[it] = s2;
  }
  __syncthreads();
  if (lane == 0) {
    float loss_x = (float)(-le[T - 1] / (double)E);
    float loss_h = 0.0f;
    for (int i = 0; i < T - 1; ++i) loss_h += (float)(-le[i] / (double)E);
    float yl_x = (float)(ly[T - 1] / (double)N);
    float yl_h = 0.0f;
    for (int i = 0; i < T - 1; ++i) yl_h += (float)(ly[i] / (double)N);
    out4[0] = loss_x;
    out4[1] = loss_h;
    out4[2] = yl_x;
    out4[3] = yl_h;
  }
}

// ============ launch ============
extern "C" void kernel_launch(void* const* d_in, const int* in_sizes, int n_in,
                              void* d_out, int out_size, void* d_ws, size_t ws_size,
                              hipStream_t stream) {
  const float* pos = (const float*)d_in[0];
  const float* s = (const float*)d_in[1];
  const int* eidx = (const int*)d_in[2];
  const int* pi = (const int*)d_in[3];
  const int* pi_h = (const int*)d_in[4];
  const int* reach = (const int*)d_in[5];
  const float* W_enc = (const float*)d_in[6];
  const float* b_enc = (const float*)d_in[7];
  const float* W_msg = (const float*)d_in[8];
  const float* b_msg = (const float*)d_in[9];
  const float* W_self = (const float*)d_in[10];
  const float* W_agg = (const float*)d_in[11];
  const float* b_upd = (const float*)d_in[12];
  const float* W_dec = (const float*)d_in[13];
  const float* b_dec = (const float*)d_in[14];

  const int N = in_sizes[0];
  const int E = in_sizes[3];
  const int T = in_sizes[4] / in_sizes[3];
  const int* src = eidx;
  const int* dst = eidx + E;

  char* w = (char*)d_ws;
  auto alloc = [&](size_t bytes) {
    char* p = w;
    w += (bytes + 255) & ~(size_t)255;
    return p;
  };
  float* xw = (float*)alloc((size_t)N * 256 * 4);
  float* agg = (float*)alloc((size_t)N * 128 * 4);
  float* h = (float*)alloc((size_t)N * 128 * 4);
  float* Wcat = (float*)alloc(256 * 256 * 4);
  float* bcat = (float*)alloc(256 * 4);
  float* u = (float*)alloc((size_t)N * 4);
  float* v = (float*)alloc((size_t)N * 4);
  float* ybuf = (float*)alloc((size_t)N * 4);
  int* cnt_d = (int*)alloc((size_t)N * 4);
  int* cnt_s = (int*)alloc((size_t)N * 4);
  int* row_ptr = (int*)alloc((size_t)(N + 1) * 4);
  int* row_ptr2 = (int*)alloc((size_t)(N + 1) * 4);
  int* csr_src = (int*)alloc((size_t)E * 4);
  int* csr_dst = (int*)alloc((size_t)E * 4);
  int* partial_d = (int*)alloc((size_t)CSR_B * N * 4);
  int* partial_s = (int*)alloc((size_t)CSR_B * N * 4);
  double* pe = (double*)alloc((size_t)T * GB * 8);
  double* py = (double*)alloc((size_t)T * GB * 8);
  const int NB2 = (N + SCAN_CHUNK - 1) / SCAN_CHUNK;
  int* bsum = (int*)alloc((size_t)2 * NB2 * 4);

  float* outy = (float*)d_out;
  float* out4 = outy + N;

  k_build_w<<<256, 256, 0, stream>>>(W_msg, W_self, b_msg, Wcat, bcat);

  const size_t lds2 = (size_t)2 * ((N + 1) >> 1) * 4;  // ~80 KB
  k_hist2<<<CSR_B, 256, lds2, stream>>>(eidx, E, N, partial_d, partial_s);
  k_colscan2<<<(2 * N + 255) / 256, 256, 0, stream>>>(partial_d, cnt_d, partial_s, cnt_s, N);
  k_bsum<<<dim3(NB2, 2), 256, 0, stream>>>(cnt_d, cnt_s, bsum, N, NB2);
  k_bscan<<<1, 64, 0, stream>>>(bsum, NB2);
  k_scanf<<<dim3(NB2, 2), 256, 0, stream>>>(cnt_d, cnt_s, bsum, row_ptr, row_ptr2, N, NB2);
  k_scatter2<<<CSR_B, 256, lds2, stream>>>(eidx, E, N, partial_d, row_ptr, csr_src, partial_s,
                                           row_ptr2, csr_dst);

  const int Nh = (N + 1) / 2;
  const int NB = (Nh + 7) / 8;

  const float* sfeat = s;
  for (int it = 0; it < T; ++it) {
    dim3 g1((N + 63) / 64, 2);
    if (it == 0)
      k_gemm<true><<<g1, 256, 0, stream>>>(pos, sfeat, h, W_enc, b_enc, Wcat, bcat, xw, N);
    else
      k_gemm<false><<<g1, 256, 0, stream>>>(pos, sfeat, h, W_enc, b_enc, Wcat, bcat, xw, N);

    k_aggmax<<<dim3(8, NB), 256, 0, stream>>>(xw, row_ptr, csr_src, agg, N, Nh);

    k_update2<<<(N + 31) / 32, 256, 0, stream>>>(agg, W_agg, b_upd, xw, W_dec, b_dec,
                                                 h, u, v, N);

    const int* tgt = (it < T - 1) ? (pi_h + (size_t)(it + 1) * E) : pi;
    const int* rrow = (it < T - 1) ? (reach + (size_t)(it + 1) * N) : (reach + (size_t)(T - 1) * N);
    k_losses<<<GB, 256, 0, stream>>>(src, dst, u, v, tgt, row_ptr, csr_src, row_ptr2, csr_dst,
                                     rrow, ybuf, outy, (it == T - 1) ? 1 : 0,
                                     pe + (size_t)it * GB, py + (size_t)it * GB, E, N);
    sfeat = ybuf;
  }
  k_final<<<1, 64, 0, stream>>>(pe, py, out4, N, E, T);
}

// Round 19
// 470.337 us; speedup vs baseline: 1.1092x; 1.0485x over previous
//
#include <hip/hip_runtime.h>

// ============ CSR build (both directions, one pass, no global atomics) ============
#define CSR_B 128

__global__ __launch_bounds__(512) void k_hist2(const int* __restrict__ eidx, int E, int N,
                                               int* __restrict__ partial_d,
                                               int* __restrict__ partial_s) {
  extern __shared__ unsigned int hist[];  // [2*nw]
  int nw = (N + 1) >> 1;
  for (int i = threadIdx.x; i < 2 * nw; i += blockDim.x) hist[i] = 0u;
  __syncthreads();
  const int* src = eidx;
  const int* dst = eidx + E;
  int chunk = (E + CSR_B - 1) / CSR_B;
  int beg = blockIdx.x * chunk, end = min(E, beg + chunk);
  for (int e = beg + threadIdx.x; e < end; e += blockDim.x) {
    int d = dst[e];
    atomicAdd(&hist[d >> 1], 1u << ((d & 1) * 16));
    int s = src[e];
    atomicAdd(&hist[nw + (s >> 1)], 1u << ((s & 1) * 16));
  }
  __syncthreads();
  for (int i = threadIdx.x; i < N; i += blockDim.x) {
    partial_d[(size_t)blockIdx.x * N + i] = (int)((hist[i >> 1] >> ((i & 1) * 16)) & 0xFFFFu);
    partial_s[(size_t)blockIdx.x * N + i] = (int)((hist[nw + (i >> 1)] >> ((i & 1) * 16)) & 0xFFFFu);
  }
}

__global__ __launch_bounds__(256) void k_colscan2(int* __restrict__ partial_d,
                                                  int* __restrict__ cnt_d,
                                                  int* __restrict__ partial_s,
                                                  int* __restrict__ cnt_s, int N) {
  int g = blockIdx.x * blockDim.x + threadIdx.x;
  int* partial;
  int* cnt;
  int bin;
  if (g < N) { partial = partial_d; cnt = cnt_d; bin = g; }
  else if (g < 2 * N) { partial = partial_s; cnt = cnt_s; bin = g - N; }
  else return;
  int run = 0;
  for (int b = 0; b < CSR_B; ++b) {
    int t = partial[(size_t)b * N + bin];
    partial[(size_t)b * N + bin] = run;
    run += t;
  }
  cnt[bin] = run;
}

// ============ hierarchical scan ============
#define SCAN_CHUNK 2048

__global__ __launch_bounds__(256) void k_bsum(const int* __restrict__ cnt_d,
                                              const int* __restrict__ cnt_s,
                                              int* __restrict__ bsum, int N, int NB2) {
  const int* cnt = blockIdx.y ? cnt_s : cnt_d;
  int base = blockIdx.x * SCAN_CHUNK;
  int hi = min(N, base + SCAN_CHUNK);
  int s = 0;
  for (int i = base + threadIdx.x; i < hi; i += 256) s += cnt[i];
#pragma unroll
  for (int off = 32; off > 0; off >>= 1) s += __shfl_down(s, off);
  __shared__ int ws[4];
  if ((threadIdx.x & 63) == 0) ws[threadIdx.x >> 6] = s;
  __syncthreads();
  if (threadIdx.x == 0) bsum[blockIdx.y * NB2 + blockIdx.x] = ws[0] + ws[1] + ws[2] + ws[3];
}

__global__ void k_bscan(int* __restrict__ bsum, int NB2) {
  if (threadIdx.x < 2) {
    int* b = bsum + threadIdx.x * NB2;
    int run = 0;
    for (int i = 0; i < NB2; ++i) {
      int t = b[i];
      b[i] = run;
      run += t;
    }
  }
}

__global__ __launch_bounds__(256) void k_scanf(const int* __restrict__ cnt_d,
                                               const int* __restrict__ cnt_s,
                                               const int* __restrict__ bsum,
                                               int* __restrict__ rp_d, int* __restrict__ rp_s,
                                               int N, int NB2) {
  const int* cnt = blockIdx.y ? cnt_s : cnt_d;
  int* rp = blockIdx.y ? rp_s : rp_d;
  const int t = threadIdx.x;
  const int idx0 = blockIdx.x * SCAN_CHUNK + t * 8;
  int vals[8];
  int s = 0;
#pragma unroll
  for (int j = 0; j < 8; ++j) {
    int i = idx0 + j;
    int v = (i < N) ? cnt[i] : 0;
    vals[j] = v;
    s += v;
  }
  __shared__ int sums[256];
  sums[t] = s;
  __syncthreads();
  for (int off = 1; off < 256; off <<= 1) {
    int v = (t >= off) ? sums[t - off] : 0;
    __syncthreads();
    sums[t] += v;
    __syncthreads();
  }
  int run = bsum[blockIdx.y * NB2 + blockIdx.x] + ((t > 0) ? sums[t - 1] : 0);
#pragma unroll
  for (int j = 0; j < 8; ++j) {
    int i = idx0 + j;
    if (i < N) {
      run += vals[j];
      rp[i + 1] = run;
    }
  }
  if (t == 0 && blockIdx.x == 0) rp[0] = 0;
}

__global__ __launch_bounds__(512) void k_scatter2(
    const int* __restrict__ eidx, int E, int N,
    const int* __restrict__ partial_d, const int* __restrict__ rp_d, int* __restrict__ csr_src,
    const int* __restrict__ partial_s, const int* __restrict__ rp_s, int* __restrict__ csr_dst) {
  extern __shared__ unsigned int cur[];  // [2*nw]
  int nw = (N + 1) >> 1;
  for (int i = threadIdx.x; i < 2 * nw; i += blockDim.x) cur[i] = 0u;
  __syncthreads();
  const int* src = eidx;
  const int* dst = eidx + E;
  int chunk = (E + CSR_B - 1) / CSR_B;
  int beg = blockIdx.x * chunk, end = min(E, beg + chunk);
  for (int e = beg + threadIdx.x; e < end; e += blockDim.x) {
    int d = dst[e], s = src[e];
    int shd = (d & 1) * 16;
    unsigned int old = atomicAdd(&cur[d >> 1], 1u << shd);
    csr_src[rp_d[d] + partial_d[(size_t)blockIdx.x * N + d] + (int)((old >> shd) & 0xFFFFu)] = s;
    int shs = (s & 1) * 16;
    unsigned int old2 = atomicAdd(&cur[nw + (s >> 1)], 1u << shs);
    csr_dst[rp_s[s] + partial_s[(size_t)blockIdx.x * N + s] + (int)((old2 >> shs) & 0xFFFFu)] = d;
  }
}

// ============ weights prep ============
__global__ void k_build_w(const float* __restrict__ W_msg, const float* __restrict__ W_self,
                          const float* __restrict__ b_msg, float* __restrict__ Wcat,
                          float* __restrict__ bcat) {
  int idx = blockIdx.x * blockDim.x + threadIdx.x;  // 256*256
  int k = idx >> 8, j = idx & 255;
  Wcat[idx] = (j < 128) ? W_msg[k * 128 + j] : W_self[k * 128 + (j - 128)];
  if (idx < 256) bcat[idx] = (idx < 128) ? b_msg[idx] : 0.0f;
}

// ============ GEMM: xw[M,256] = x[M,256] @ Wcat + bcat ============
// BM=64, BN=128, BK=16, 256 thr, 4 rows x 8 cols/thread + register-prefetch
// (commit regs->LDS, barrier, issue next loads, compute, barrier).
// NOTE: single-buffered on purpose — explicit LDS dbuf raises VGPR 48->128
// and regresses (measured twice, R4/R15).
__device__ __forceinline__ float4 enc4(float p, float sf, float4 we0, float4 we1, float4 be) {
  float4 r;
  r.x = fmaxf(fmaf(p, we0.x, fmaf(sf, we1.x, be.x)), 0.f);
  r.y = fmaxf(fmaf(p, we0.y, fmaf(sf, we1.y, be.y)), 0.f);
  r.z = fmaxf(fmaf(p, we0.z, fmaf(sf, we1.z, be.z)), 0.f);
  r.w = fmaxf(fmaf(p, we0.w, fmaf(sf, we1.w, be.w)), 0.f);
  return r;
}

template <bool IT0>
__global__ __launch_bounds__(256) void k_gemm(
    const float* __restrict__ pos, const float* __restrict__ sfeat,
    const float* __restrict__ hsrc, const float* __restrict__ W_enc,
    const float* __restrict__ b_enc, const float* __restrict__ B,
    const float* __restrict__ bias, float* __restrict__ C, int M) {
  __shared__ float As[16][68];    // [k][row], +4 pad
  __shared__ float Bs[16][132];   // [k][col], +4 pad
  const int m0 = blockIdx.x * 64, n0 = blockIdx.y * 128;
  const int t = threadIdx.x;
  const int ty = t >> 4;          // [0,16): rows ty*4..ty*4+3
  const int tx = t & 15;          // [0,16): cols tx*4 and 64+tx*4
  const int lr = t >> 2, lq = (t & 3) << 2;  // A-load: row [0,64), col quad
  const int row_ld = m0 + lr;
  const bool valid = row_ld < M;
  float p = 0.f, sf = 0.f;
  if (valid) { p = pos[row_ld]; sf = sfeat[row_ld]; }
  const int bk0 = t >> 5, bc0 = (t & 31) << 2;
  const int bk1 = (t + 256) >> 5, bc1 = bc0;
  const int KMAX = IT0 ? 128 : 256;

  auto loadA = [&](int k0) -> float4 {
    float4 av = make_float4(0.f, 0.f, 0.f, 0.f);
    const int col = k0 + lq;
    if (valid) {
      if (col < 128) {
        float4 we0 = *reinterpret_cast<const float4*>(&W_enc[col]);
        float4 we1 = *reinterpret_cast<const float4*>(&W_enc[128 + col]);
        float4 be = *reinterpret_cast<const float4*>(&b_enc[col]);
        av = enc4(p, sf, we0, we1, be);
      } else {
        av = *reinterpret_cast<const float4*>(&hsrc[(size_t)row_ld * 128 + col - 128]);
      }
    }
    return av;
  };

  float4 ra = loadA(0);
  float4 rb0 = *reinterpret_cast<const float4*>(&B[(size_t)bk0 * 256 + n0 + bc0]);
  float4 rb1 = *reinterpret_cast<const float4*>(&B[(size_t)bk1 * 256 + n0 + bc1]);

  float acc[4][8] = {};
  for (int k0 = 0; k0 < KMAX; k0 += 16) {
    As[lq + 0][lr] = ra.x;
    As[lq + 1][lr] = ra.y;
    As[lq + 2][lr] = ra.z;
    As[lq + 3][lr] = ra.w;
    *reinterpret_cast<float4*>(&Bs[bk0][bc0]) = rb0;
    *reinterpret_cast<float4*>(&Bs[bk1][bc1]) = rb1;
    __syncthreads();
    const bool more = (k0 + 16) < KMAX;
    if (more) {
      ra = loadA(k0 + 16);
      rb0 = *reinterpret_cast<const float4*>(&B[(size_t)(k0 + 16 + bk0) * 256 + n0 + bc0]);
      rb1 = *reinterpret_cast<const float4*>(&B[(size_t)(k0 + 16 + bk1) * 256 + n0 + bc1]);
    }
#pragma unroll
    for (int k = 0; k < 16; ++k) {
      float4 a4 = *reinterpret_cast<const float4*>(&As[k][ty * 4]);
      float4 b0 = *reinterpret_cast<const float4*>(&Bs[k][tx * 4]);
      float4 b1 = *reinterpret_cast<const float4*>(&Bs[k][64 + tx * 4]);
      const float a[4] = {a4.x, a4.y, a4.z, a4.w};
      const float bb[8] = {b0.x, b0.y, b0.z, b0.w, b1.x, b1.y, b1.z, b1.w};
#pragma unroll
      for (int i = 0; i < 4; ++i)
#pragma unroll
        for (int j = 0; j < 8; ++j) acc[i][j] = fmaf(a[i], bb[j], acc[i][j]);
    }
    __syncthreads();
  }
  float4 bi0 = *reinterpret_cast<const float4*>(&bias[n0 + tx * 4]);
  float4 bi1 = *reinterpret_cast<const float4*>(&bias[n0 + 64 + tx * 4]);
#pragma unroll
  for (int i = 0; i < 4; ++i) {
    int row = m0 + ty * 4 + i;
    if (row < M) {
      float4 o0 = make_float4(acc[i][0] + bi0.x, acc[i][1] + bi0.y, acc[i][2] + bi0.z,
                              acc[i][3] + bi0.w);
      float4 o1 = make_float4(acc[i][4] + bi1.x, acc[i][5] + bi1.y, acc[i][6] + bi1.z,
                              acc[i][7] + bi1.w);
      *reinterpret_cast<float4*>(&C[(size_t)row * 256 + n0 + tx * 4]) = o0;
      *reinterpret_cast<float4*>(&C[(size_t)row * 256 + n0 + 64 + tx * 4]) = o1;
    }
  }
}

// ============ aggmax: feature-chunked for per-XCD L2 residence, 8-deep MLP ============
__global__ __launch_bounds__(256) void k_aggmax(
    const float* __restrict__ xw, const int* __restrict__ row_ptr,
    const int* __restrict__ csr_src, float* __restrict__ agg, int N, int Nh) {
  const int cx = blockIdx.x & 7;
  const int chunk = cx & 3;
  const int half = cx >> 2;
  const int hw = threadIdx.x >> 5;
  const int sub = threadIdx.x & 31;
  const int node = half * Nh + blockIdx.y * 8 + hw;
  const int hi = half ? N : Nh;
  if (node >= hi) return;
  const float* base = xw + chunk * 32 + sub;
  const int beg = row_ptr[node], end = row_ptr[node + 1];
  float m0 = 0.f, m1 = 0.f, m2 = 0.f, m3 = 0.f;
  float m4 = 0.f, m5 = 0.f, m6 = 0.f, m7 = 0.f;
  int i = beg;
  for (; i + 7 < end; i += 8) {  // 8 independent gathers in flight
    int e0 = csr_src[i + 0], e1 = csr_src[i + 1], e2 = csr_src[i + 2], e3 = csr_src[i + 3];
    int e4 = csr_src[i + 4], e5 = csr_src[i + 5], e6 = csr_src[i + 6], e7 = csr_src[i + 7];
    float f0 = base[(size_t)e0 * 256];
    float f1 = base[(size_t)e1 * 256];
    float f2 = base[(size_t)e2 * 256];
    float f3 = base[(size_t)e3 * 256];
    float f4 = base[(size_t)e4 * 256];
    float f5 = base[(size_t)e5 * 256];
    float f6 = base[(size_t)e6 * 256];
    float f7 = base[(size_t)e7 * 256];
    m0 = fmaxf(m0, f0); m1 = fmaxf(m1, f1);
    m2 = fmaxf(m2, f2); m3 = fmaxf(m3, f3);
    m4 = fmaxf(m4, f4); m5 = fmaxf(m5, f5);
    m6 = fmaxf(m6, f6); m7 = fmaxf(m7, f7);
  }
  for (; i < end; ++i) m0 = fmaxf(m0, base[(size_t)csr_src[i] * 256]);
  m0 = fmaxf(fmaxf(fmaxf(m0, m1), fmaxf(m2, m3)),
             fmaxf(fmaxf(m4, m5), fmaxf(m6, m7)));
  agg[(size_t)node * 128 + chunk * 32 + sub] = m0;
}

// ============ update GEMM: h = relu(agg@W_agg + self + b_upd); fused u,v ============
__global__ __launch_bounds__(256) void k_update2(
    const float* __restrict__ agg, const float* __restrict__ W_agg,
    const float* __restrict__ b_upd, const float* __restrict__ xw,
    const float* __restrict__ W_dec, const float* __restrict__ b_dec,
    float* __restrict__ h, float* __restrict__ u, float* __restrict__ v, int M) {
  __shared__ float AsT[32][33];
  __shared__ float Bs[32][128];
  const int m0 = blockIdx.x * 32;
  const int t = threadIdx.x;
  const int ty = t >> 5, tx = t & 31;
  const int lar = t >> 3, lac = (t & 7) << 2;
  float acc[4][4] = {};
  for (int k0 = 0; k0 < 128; k0 += 32) {
    {
      float4 av = make_float4(0.f, 0.f, 0.f, 0.f);
      int row = m0 + lar;
      if (row < M) av = *reinterpret_cast<const float4*>(&agg[(size_t)row * 128 + k0 + lac]);
      AsT[lac + 0][lar] = av.x;
      AsT[lac + 1][lar] = av.y;
      AsT[lac + 2][lar] = av.z;
      AsT[lac + 3][lar] = av.w;
#pragma unroll
      for (int p = 0; p < 4; ++p) {
        int br = (t >> 5) + p * 8;
        *reinterpret_cast<float4*>(&Bs[br][tx * 4]) =
            *reinterpret_cast<const float4*>(&W_agg[(size_t)(k0 + br) * 128 + tx * 4]);
      }
    }
    __syncthreads();
#pragma unroll
    for (int k = 0; k < 32; ++k) {
      float4 a4 = *reinterpret_cast<const float4*>(&AsT[k][ty * 4]);
      float4 b4 = *reinterpret_cast<const float4*>(&Bs[k][tx * 4]);
      const float aa[4] = {a4.x, a4.y, a4.z, a4.w};
      const float bb[4] = {b4.x, b4.y, b4.z, b4.w};
#pragma unroll
      for (int j = 0; j < 4; ++j)
#pragma unroll
        for (int c = 0; c < 4; ++c) acc[j][c] = fmaf(aa[j], bb[c], acc[j][c]);
    }
    __syncthreads();
  }
  const float4 bu4 = *reinterpret_cast<const float4*>(&b_upd[tx * 4]);
  const float4 wdu = *reinterpret_cast<const float4*>(&W_dec[tx * 4]);
  const float4 wdv = *reinterpret_cast<const float4*>(&W_dec[128 + tx * 4]);
  const float bd = b_dec[0];
#pragma unroll
  for (int j = 0; j < 4; ++j) {
    int row = m0 + ty * 4 + j;
    if (row >= M) continue;
    float4 sf = *reinterpret_cast<const float4*>(&xw[(size_t)row * 256 + 128 + tx * 4]);
    float4 h4;
    h4.x = fmaxf(acc[j][0] + sf.x + bu4.x, 0.f);
    h4.y = fmaxf(acc[j][1] + sf.y + bu4.y, 0.f);
    h4.z = fmaxf(acc[j][2] + sf.z + bu4.z, 0.f);
    h4.w = fmaxf(acc[j][3] + sf.w + bu4.w, 0.f);
    *reinterpret_cast<float4*>(&h[(size_t)row * 128 + tx * 4]) = h4;
    float up = h4.x * wdu.x + h4.y * wdu.y + h4.z * wdu.z + h4.w * wdu.w;
    float vp = h4.x * wdv.x + h4.y * wdv.y + h4.z * wdv.z + h4.w * wdv.w;
#pragma unroll
    for (int m = 16; m > 0; m >>= 1) {
      up += __shfl_xor(up, m);
      vp += __shfl_xor(vp, m);
    }
    if (tx == 0) {
      u[row] = up + bd;
      v[row] = vp;
    }
  }
}

// ============ fused losses: edge BCE partials + node y/max + y-BCE partials ============
#define GB 512
__global__ __launch_bounds__(256) void k_losses(
    const int* __restrict__ src, const int* __restrict__ dst, const float* __restrict__ u,
    const float* __restrict__ v, const int* __restrict__ tgt, const int* __restrict__ row_ptr,
    const int* __restrict__ csr_src, const int* __restrict__ row_ptr2,
    const int* __restrict__ csr_dst, const int* __restrict__ reach_row,
    float* __restrict__ ybuf, float* __restrict__ yout, int write_out,
    double* __restrict__ pe_slot, double* __restrict__ py_slot, int E, int N) {
  __shared__ double wsum[4];
  double term = 0.0;
  for (int e = blockIdx.x * blockDim.x + threadIdx.x; e < E; e += GB * 256) {
    float l = u[src[e]] + v[dst[e]];
    float xsel = (tgt[e] != 0) ? -l : l;
    float sp = log1pf(expf(xsel));
    term += (double)fmaxf(-sp, -100.0f);
  }
#pragma unroll
  for (int off = 32; off > 0; off >>= 1) term += __shfl_down(term, off);
  if ((threadIdx.x & 63) == 0) wsum[threadIdx.x >> 6] = term;
  __syncthreads();
  if (threadIdx.x == 0) pe_slot[blockIdx.x] = wsum[0] + wsum[1] + wsum[2] + wsum[3];
  __syncthreads();
  double c = 0.0;
  for (int n = blockIdx.x * blockDim.x + threadIdx.x; n < N; n += GB * 256) {
    float mu = -INFINITY, mv = -INFINITY;
    // incoming-u max, 4 gathers in flight
    {
      const int b1 = row_ptr[n], e1 = row_ptr[n + 1];
      int i = b1;
      float a0 = -INFINITY, a1 = -INFINITY, a2 = -INFINITY, a3 = -INFINITY;
      for (; i + 3 < e1; i += 4) {
        int s0 = csr_src[i], s1 = csr_src[i + 1], s2 = csr_src[i + 2], s3 = csr_src[i + 3];
        float u0 = u[s0], u1 = u[s1], u2 = u[s2], u3 = u[s3];
        a0 = fmaxf(a0, u0); a1 = fmaxf(a1, u1);
        a2 = fmaxf(a2, u2); a3 = fmaxf(a3, u3);
      }
      for (; i < e1; ++i) a0 = fmaxf(a0, u[csr_src[i]]);
      mu = fmaxf(fmaxf(a0, a1), fmaxf(a2, a3));
    }
    // outgoing-v max, 4 gathers in flight
    {
      const int b2 = row_ptr2[n], e2 = row_ptr2[n + 1];
      int i = b2;
      float a0 = -INFINITY, a1 = -INFINITY, a2 = -INFINITY, a3 = -INFINITY;
      for (; i + 3 < e2; i += 4) {
        int d0 = csr_dst[i], d1 = csr_dst[i + 1], d2 = csr_dst[i + 2], d3 = csr_dst[i + 3];
        float v0 = v[d0], v1 = v[d1], v2 = v[d2], v3 = v[d3];
        a0 = fmaxf(a0, v0); a1 = fmaxf(a1, v1);
        a2 = fmaxf(a2, v2); a3 = fmaxf(a3, v3);
      }
      for (; i < e2; ++i) a0 = fmaxf(a0, v[csr_dst[i]]);
      mv = fmaxf(fmaxf(a0, a1), fmaxf(a2, a3));
    }
    float m = fmaxf(mu + v[n], u[n] + mv);
    float a = 1.0f / (1.0f + expf(-m));
    float yv = (a >= 0.8f) ? 1.0f : 0.0f;
    ybuf[n] = yv;
    if (write_out) yout[n] = yv;
    if ((float)reach_row[n] != yv) c = 100.0;
  }
#pragma unroll
  for (int off = 32; off > 0; off >>= 1) c += __shfl_down(c, off);
  if ((threadIdx.x & 63) == 0) wsum[threadIdx.x >> 6] = c;
  __syncthreads();
  if (threadIdx.x == 0) py_slot[blockIdx.x] = wsum[0] + wsum[1] + wsum[2] + wsum[3];
}

__global__ void k_final(const double* __restrict__ pe, const double* __restrict__ py,
                        float* __restrict__ out4, int N, int E, int T) {
  __shared__ double le[8], ly[8];
  int lane = threadIdx.x;  // 64 threads
  for (int it = 0; it < T; ++it) {
    double s = 0.0;
    for (int i = lane; i < GB; i += 64) s += pe[(size_t)it * GB + i];
#pragma unroll
    for (int off = 32; off > 0; off >>= 1) s += __shfl_down(s, off);
    if (lane == 0) le[it] = s;
    double s2 = 0.0;
    for (int i = lane; i < GB; i += 64) s2 += py[(size_t)it * GB + i];
#pragma unroll
    for (int off = 32; off > 0; off >>= 1) s2 += __shfl_down(s2, off);
    if (lane == 0) ly[it] = s2;
  }
  __syncthreads();
  if (lane == 0) {
    float loss_x = (float)(-le[T - 1] / (double)E);
    float loss_h = 0.0f;
    for (int i = 0; i < T - 1; ++i) loss_h += (float)(-le[i] / (double)E);
    float yl_x = (float)(ly[T - 1] / (double)N);
    float yl_h = 0.0f;
    for (int i = 0; i < T - 1; ++i) yl_h += (float)(ly[i] / (double)N);
    out4[0] = loss_x;
    out4[1] = loss_h;
    out4[2] = yl_x;
    out4[3] = yl_h;
  }
}

// ============ launch ============
extern "C" void kernel_launch(void* const* d_in, const int* in_sizes, int n_in,
                              void* d_out, int out_size, void* d_ws, size_t ws_size,
                              hipStream_t stream) {
  const float* pos = (const float*)d_in[0];
  const float* s = (const float*)d_in[1];
  const int* eidx = (const int*)d_in[2];
  const int* pi = (const int*)d_in[3];
  const int* pi_h = (const int*)d_in[4];
  const int* reach = (const int*)d_in[5];
  const float* W_enc = (const float*)d_in[6];
  const float* b_enc = (const float*)d_in[7];
  const float* W_msg = (const float*)d_in[8];
  const float* b_msg = (const float*)d_in[9];
  const float* W_self = (const float*)d_in[10];
  const float* W_agg = (const float*)d_in[11];
  const float* b_upd = (const float*)d_in[12];
  const float* W_dec = (const float*)d_in[13];
  const float* b_dec = (const float*)d_in[14];

  const int N = in_sizes[0];
  const int E = in_sizes[3];
  const int T = in_sizes[4] / in_sizes[3];
  const int* src = eidx;
  const int* dst = eidx + E;

  char* w = (char*)d_ws;
  auto alloc = [&](size_t bytes) {
    char* p = w;
    w += (bytes + 255) & ~(size_t)255;
    return p;
  };
  float* xw = (float*)alloc((size_t)N * 256 * 4);
  float* agg = (float*)alloc((size_t)N * 128 * 4);
  float* h = (float*)alloc((size_t)N * 128 * 4);
  float* Wcat = (float*)alloc(256 * 256 * 4);
  float* bcat = (float*)alloc(256 * 4);
  float* u = (float*)alloc((size_t)N * 4);
  float* v = (float*)alloc((size_t)N * 4);
  float* ybuf = (float*)alloc((size_t)N * 4);
  int* cnt_d = (int*)alloc((size_t)N * 4);
  int* cnt_s = (int*)alloc((size_t)N * 4);
  int* row_ptr = (int*)alloc((size_t)(N + 1) * 4);
  int* row_ptr2 = (int*)alloc((size_t)(N + 1) * 4);
  int* csr_src = (int*)alloc((size_t)E * 4);
  int* csr_dst = (int*)alloc((size_t)E * 4);
  int* partial_d = (int*)alloc((size_t)CSR_B * N * 4);
  int* partial_s = (int*)alloc((size_t)CSR_B * N * 4);
  double* pe = (double*)alloc((size_t)T * GB * 8);
  double* py = (double*)alloc((size_t)T * GB * 8);
  const int NB2 = (N + SCAN_CHUNK - 1) / SCAN_CHUNK;
  int* bsum = (int*)alloc((size_t)2 * NB2 * 4);

  float* outy = (float*)d_out;
  float* out4 = outy + N;

  k_build_w<<<256, 256, 0, stream>>>(W_msg, W_self, b_msg, Wcat, bcat);

  const size_t lds2 = (size_t)2 * ((N + 1) >> 1) * 4;  // ~80 KB
  k_hist2<<<CSR_B, 512, lds2, stream>>>(eidx, E, N, partial_d, partial_s);
  k_colscan2<<<(2 * N + 255) / 256, 256, 0, stream>>>(partial_d, cnt_d, partial_s, cnt_s, N);
  k_bsum<<<dim3(NB2, 2), 256, 0, stream>>>(cnt_d, cnt_s, bsum, N, NB2);
  k_bscan<<<1, 64, 0, stream>>>(bsum, NB2);
  k_scanf<<<dim3(NB2, 2), 256, 0, stream>>>(cnt_d, cnt_s, bsum, row_ptr, row_ptr2, N, NB2);
  k_scatter2<<<CSR_B, 512, lds2, stream>>>(eidx, E, N, partial_d, row_ptr, csr_src, partial_s,
                                           row_ptr2, csr_dst);

  const int Nh = (N + 1) / 2;
  const int NB = (Nh + 7) / 8;

  const float* sfeat = s;
  for (int it = 0; it < T; ++it) {
    dim3 g1((N + 63) / 64, 2);
    if (it == 0)
      k_gemm<true><<<g1, 256, 0, stream>>>(pos, sfeat, h, W_enc, b_enc, Wcat, bcat, xw, N);
    else
      k_gemm<false><<<g1, 256, 0, stream>>>(pos, sfeat, h, W_enc, b_enc, Wcat, bcat, xw, N);

    k_aggmax<<<dim3(8, NB), 256, 0, stream>>>(xw, row_ptr, csr_src, agg, N, Nh);

    k_update2<<<(N + 31) / 32, 256, 0, stream>>>(agg, W_agg, b_upd, xw, W_dec, b_dec,
                                                 h, u, v, N);

    const int* tgt = (it < T - 1) ? (pi_h + (size_t)(it + 1) * E) : pi;
    const int* rrow = (it < T - 1) ? (reach + (size_t)(it + 1) * N) : (reach + (size_t)(T - 1) * N);
    k_losses<<<GB, 256, 0, stream>>>(src, dst, u, v, tgt, row_ptr, csr_src, row_ptr2, csr_dst,
                                     rrow, ybuf, outy, (it == T - 1) ? 1 : 0,
                                     pe + (size_t)it * GB, py + (size_t)it * GB, E, N);
    sfeat = ybuf;
  }
  k_final<<<1, 64, 0, stream>>>(pe, py, out4, N, E, T);
}

// Round 20
// 467.602 us; speedup vs baseline: 1.1157x; 1.0058x over previous
//
#include <hip/hip_runtime.h>

// ============ CSR build (both directions, one pass, no global atomics) ============
#define CSR_B 128

__global__ __launch_bounds__(512) void k_hist2(const int* __restrict__ eidx, int E, int N,
                                               int* __restrict__ partial_d,
                                               int* __restrict__ partial_s) {
  extern __shared__ unsigned int hist[];  // [2*nw]
  int nw = (N + 1) >> 1;
  for (int i = threadIdx.x; i < 2 * nw; i += blockDim.x) hist[i] = 0u;
  __syncthreads();
  const int* src = eidx;
  const int* dst = eidx + E;
  int chunk = (E + CSR_B - 1) / CSR_B;
  int beg = blockIdx.x * chunk, end = min(E, beg + chunk);
  for (int e = beg + threadIdx.x; e < end; e += blockDim.x) {
    int d = dst[e];
    atomicAdd(&hist[d >> 1], 1u << ((d & 1) * 16));
    int s = src[e];
    atomicAdd(&hist[nw + (s >> 1)], 1u << ((s & 1) * 16));
  }
  __syncthreads();
  for (int i = threadIdx.x; i < N; i += blockDim.x) {
    partial_d[(size_t)blockIdx.x * N + i] = (int)((hist[i >> 1] >> ((i & 1) * 16)) & 0xFFFFu);
    partial_s[(size_t)blockIdx.x * N + i] = (int)((hist[nw + (i >> 1)] >> ((i & 1) * 16)) & 0xFFFFu);
  }
}

__global__ __launch_bounds__(256) void k_colscan2(int* __restrict__ partial_d,
                                                  int* __restrict__ cnt_d,
                                                  int* __restrict__ partial_s,
                                                  int* __restrict__ cnt_s, int N) {
  int g = blockIdx.x * blockDim.x + threadIdx.x;
  int* partial;
  int* cnt;
  int bin;
  if (g < N) { partial = partial_d; cnt = cnt_d; bin = g; }
  else if (g < 2 * N) { partial = partial_s; cnt = cnt_s; bin = g - N; }
  else return;
  int run = 0;
  for (int b = 0; b < CSR_B; ++b) {
    int t = partial[(size_t)b * N + bin];
    partial[(size_t)b * N + bin] = run;
    run += t;
  }
  cnt[bin] = run;
}

// ============ hierarchical scan ============
#define SCAN_CHUNK 2048

__global__ __launch_bounds__(256) void k_bsum(const int* __restrict__ cnt_d,
                                              const int* __restrict__ cnt_s,
                                              int* __restrict__ bsum, int N, int NB2) {
  const int* cnt = blockIdx.y ? cnt_s : cnt_d;
  int base = blockIdx.x * SCAN_CHUNK;
  int hi = min(N, base + SCAN_CHUNK);
  int s = 0;
  for (int i = base + threadIdx.x; i < hi; i += 256) s += cnt[i];
#pragma unroll
  for (int off = 32; off > 0; off >>= 1) s += __shfl_down(s, off);
  __shared__ int ws[4];
  if ((threadIdx.x & 63) == 0) ws[threadIdx.x >> 6] = s;
  __syncthreads();
  if (threadIdx.x == 0) bsum[blockIdx.y * NB2 + blockIdx.x] = ws[0] + ws[1] + ws[2] + ws[3];
}

__global__ void k_bscan(int* __restrict__ bsum, int NB2) {
  if (threadIdx.x < 2) {
    int* b = bsum + threadIdx.x * NB2;
    int run = 0;
    for (int i = 0; i < NB2; ++i) {
      int t = b[i];
      b[i] = run;
      run += t;
    }
  }
}

__global__ __launch_bounds__(256) void k_scanf(const int* __restrict__ cnt_d,
                                               const int* __restrict__ cnt_s,
                                               const int* __restrict__ bsum,
                                               int* __restrict__ rp_d, int* __restrict__ rp_s,
                                               int N, int NB2) {
  const int* cnt = blockIdx.y ? cnt_s : cnt_d;
  int* rp = blockIdx.y ? rp_s : rp_d;
  const int t = threadIdx.x;
  const int idx0 = blockIdx.x * SCAN_CHUNK + t * 8;
  int vals[8];
  int s = 0;
#pragma unroll
  for (int j = 0; j < 8; ++j) {
    int i = idx0 + j;
    int v = (i < N) ? cnt[i] : 0;
    vals[j] = v;
    s += v;
  }
  __shared__ int sums[256];
  sums[t] = s;
  __syncthreads();
  for (int off = 1; off < 256; off <<= 1) {
    int v = (t >= off) ? sums[t - off] : 0;
    __syncthreads();
    sums[t] += v;
    __syncthreads();
  }
  int run = bsum[blockIdx.y * NB2 + blockIdx.x] + ((t > 0) ? sums[t - 1] : 0);
#pragma unroll
  for (int j = 0; j < 8; ++j) {
    int i = idx0 + j;
    if (i < N) {
      run += vals[j];
      rp[i + 1] = run;
    }
  }
  if (t == 0 && blockIdx.x == 0) rp[0] = 0;
}

__global__ __launch_bounds__(512) void k_scatter2(
    const int* __restrict__ eidx, int E, int N,
    const int* __restrict__ partial_d, const int* __restrict__ rp_d, int* __restrict__ csr_src,
    const int* __restrict__ partial_s, const int* __restrict__ rp_s, int* __restrict__ csr_dst) {
  extern __shared__ unsigned int cur[];  // [2*nw]
  int nw = (N + 1) >> 1;
  for (int i = threadIdx.x; i < 2 * nw; i += blockDim.x) cur[i] = 0u;
  __syncthreads();
  const int* src = eidx;
  const int* dst = eidx + E;
  int chunk = (E + CSR_B - 1) / CSR_B;
  int beg = blockIdx.x * chunk, end = min(E, beg + chunk);
  for (int e = beg + threadIdx.x; e < end; e += blockDim.x) {
    int d = dst[e], s = src[e];
    int shd = (d & 1) * 16;
    unsigned int old = atomicAdd(&cur[d >> 1], 1u << shd);
    csr_src[rp_d[d] + partial_d[(size_t)blockIdx.x * N + d] + (int)((old >> shd) & 0xFFFFu)] = s;
    int shs = (s & 1) * 16;
    unsigned int old2 = atomicAdd(&cur[nw + (s >> 1)], 1u << shs);
    csr_dst[rp_s[s] + partial_s[(size_t)blockIdx.x * N + s] + (int)((old2 >> shs) & 0xFFFFu)] = d;
  }
}

// ============ weights prep ============
__global__ void k_build_w(const float* __restrict__ W_msg, const float* __restrict__ W_self,
                          const float* __restrict__ b_msg, float* __restrict__ Wcat,
                          float* __restrict__ bcat) {
  int idx = blockIdx.x * blockDim.x + threadIdx.x;  // 256*256
  int k = idx >> 8, j = idx & 255;
  Wcat[idx] = (j < 128) ? W_msg[k * 128 + j] : W_self[k * 128 + (j - 128)];
  if (idx < 256) bcat[idx] = (idx < 128) ? b_msg[idx] : 0.0f;
}

// ============ GEMM: xw[M,256] = x[M,256] @ Wcat + bcat ============
// BM=64, BN=128, BK=16, 256 thr, 4 rows x 8 cols/thread + register-prefetch
// (commit regs->LDS, barrier, issue next loads, compute, barrier).
// NOTE: single-buffered on purpose — explicit LDS dbuf raises VGPR 48->128
// and regresses (measured twice, R4/R15).
__device__ __forceinline__ float4 enc4(float p, float sf, float4 we0, float4 we1, float4 be) {
  float4 r;
  r.x = fmaxf(fmaf(p, we0.x, fmaf(sf, we1.x, be.x)), 0.f);
  r.y = fmaxf(fmaf(p, we0.y, fmaf(sf, we1.y, be.y)), 0.f);
  r.z = fmaxf(fmaf(p, we0.z, fmaf(sf, we1.z, be.z)), 0.f);
  r.w = fmaxf(fmaf(p, we0.w, fmaf(sf, we1.w, be.w)), 0.f);
  return r;
}

template <bool IT0>
__global__ __launch_bounds__(256) void k_gemm(
    const float* __restrict__ pos, const float* __restrict__ sfeat,
    const float* __restrict__ hsrc, const float* __restrict__ W_enc,
    const float* __restrict__ b_enc, const float* __restrict__ B,
    const float* __restrict__ bias, float* __restrict__ C, int M) {
  __shared__ float As[16][68];    // [k][row], +4 pad
  __shared__ float Bs[16][132];   // [k][col], +4 pad
  const int m0 = blockIdx.x * 64, n0 = blockIdx.y * 128;
  const int t = threadIdx.x;
  const int ty = t >> 4;          // [0,16): rows ty*4..ty*4+3
  const int tx = t & 15;          // [0,16): cols tx*4 and 64+tx*4
  const int lr = t >> 2, lq = (t & 3) << 2;  // A-load: row [0,64), col quad
  const int row_ld = m0 + lr;
  const bool valid = row_ld < M;
  float p = 0.f, sf = 0.f;
  if (valid) { p = pos[row_ld]; sf = sfeat[row_ld]; }
  const int bk0 = t >> 5, bc0 = (t & 31) << 2;
  const int bk1 = (t + 256) >> 5, bc1 = bc0;
  const int KMAX = IT0 ? 128 : 256;

  auto loadA = [&](int k0) -> float4 {
    float4 av = make_float4(0.f, 0.f, 0.f, 0.f);
    const int col = k0 + lq;
    if (valid) {
      if (col < 128) {
        float4 we0 = *reinterpret_cast<const float4*>(&W_enc[col]);
        float4 we1 = *reinterpret_cast<const float4*>(&W_enc[128 + col]);
        float4 be = *reinterpret_cast<const float4*>(&b_enc[col]);
        av = enc4(p, sf, we0, we1, be);
      } else {
        av = *reinterpret_cast<const float4*>(&hsrc[(size_t)row_ld * 128 + col - 128]);
      }
    }
    return av;
  };

  float4 ra = loadA(0);
  float4 rb0 = *reinterpret_cast<const float4*>(&B[(size_t)bk0 * 256 + n0 + bc0]);
  float4 rb1 = *reinterpret_cast<const float4*>(&B[(size_t)bk1 * 256 + n0 + bc1]);

  float acc[4][8] = {};
  for (int k0 = 0; k0 < KMAX; k0 += 16) {
    As[lq + 0][lr] = ra.x;
    As[lq + 1][lr] = ra.y;
    As[lq + 2][lr] = ra.z;
    As[lq + 3][lr] = ra.w;
    *reinterpret_cast<float4*>(&Bs[bk0][bc0]) = rb0;
    *reinterpret_cast<float4*>(&Bs[bk1][bc1]) = rb1;
    __syncthreads();
    const bool more = (k0 + 16) < KMAX;
    if (more) {
      ra = loadA(k0 + 16);
      rb0 = *reinterpret_cast<const float4*>(&B[(size_t)(k0 + 16 + bk0) * 256 + n0 + bc0]);
      rb1 = *reinterpret_cast<const float4*>(&B[(size_t)(k0 + 16 + bk1) * 256 + n0 + bc1]);
    }
#pragma unroll
    for (int k = 0; k < 16; ++k) {
      float4 a4 = *reinterpret_cast<const float4*>(&As[k][ty * 4]);
      float4 b0 = *reinterpret_cast<const float4*>(&Bs[k][tx * 4]);
      float4 b1 = *reinterpret_cast<const float4*>(&Bs[k][64 + tx * 4]);
      const float a[4] = {a4.x, a4.y, a4.z, a4.w};
      const float bb[8] = {b0.x, b0.y, b0.z, b0.w, b1.x, b1.y, b1.z, b1.w};
#pragma unroll
      for (int i = 0; i < 4; ++i)
#pragma unroll
        for (int j = 0; j < 8; ++j) acc[i][j] = fmaf(a[i], bb[j], acc[i][j]);
    }
    __syncthreads();
  }
  float4 bi0 = *reinterpret_cast<const float4*>(&bias[n0 + tx * 4]);
  float4 bi1 = *reinterpret_cast<const float4*>(&bias[n0 + 64 + tx * 4]);
#pragma unroll
  for (int i = 0; i < 4; ++i) {
    int row = m0 + ty * 4 + i;
    if (row < M) {
      float4 o0 = make_float4(acc[i][0] + bi0.x, acc[i][1] + bi0.y, acc[i][2] + bi0.z,
                              acc[i][3] + bi0.w);
      float4 o1 = make_float4(acc[i][4] + bi1.x, acc[i][5] + bi1.y, acc[i][6] + bi1.z,
                              acc[i][7] + bi1.w);
      *reinterpret_cast<float4*>(&C[(size_t)row * 256 + n0 + tx * 4]) = o0;
      *reinterpret_cast<float4*>(&C[(size_t)row * 256 + n0 + 64 + tx * 4]) = o1;
    }
  }
}

// ============ aggmax: feature-chunked for per-XCD L2 residence, 8-deep MLP ============
__global__ __launch_bounds__(256) void k_aggmax(
    const float* __restrict__ xw, const int* __restrict__ row_ptr,
    const int* __restrict__ csr_src, float* __restrict__ agg, int N, int Nh) {
  const int cx = blockIdx.x & 7;
  const int chunk = cx & 3;
  const int half = cx >> 2;
  const int hw = threadIdx.x >> 5;
  const int sub = threadIdx.x & 31;
  const int node = half * Nh + blockIdx.y * 8 + hw;
  const int hi = half ? N : Nh;
  if (node >= hi) return;
  const float* base = xw + chunk * 32 + sub;
  const int beg = row_ptr[node], end = row_ptr[node + 1];
  float m0 = 0.f, m1 = 0.f, m2 = 0.f, m3 = 0.f;
  float m4 = 0.f, m5 = 0.f, m6 = 0.f, m7 = 0.f;
  int i = beg;
  for (; i + 7 < end; i += 8) {  // 8 independent gathers in flight
    int e0 = csr_src[i + 0], e1 = csr_src[i + 1], e2 = csr_src[i + 2], e3 = csr_src[i + 3];
    int e4 = csr_src[i + 4], e5 = csr_src[i + 5], e6 = csr_src[i + 6], e7 = csr_src[i + 7];
    float f0 = base[(size_t)e0 * 256];
    float f1 = base[(size_t)e1 * 256];
    float f2 = base[(size_t)e2 * 256];
    float f3 = base[(size_t)e3 * 256];
    float f4 = base[(size_t)e4 * 256];
    float f5 = base[(size_t)e5 * 256];
    float f6 = base[(size_t)e6 * 256];
    float f7 = base[(size_t)e7 * 256];
    m0 = fmaxf(m0, f0); m1 = fmaxf(m1, f1);
    m2 = fmaxf(m2, f2); m3 = fmaxf(m3, f3);
    m4 = fmaxf(m4, f4); m5 = fmaxf(m5, f5);
    m6 = fmaxf(m6, f6); m7 = fmaxf(m7, f7);
  }
  for (; i < end; ++i) m0 = fmaxf(m0, base[(size_t)csr_src[i] * 256]);
  m0 = fmaxf(fmaxf(fmaxf(m0, m1), fmaxf(m2, m3)),
             fmaxf(fmaxf(m4, m5), fmaxf(m6, m7)));
  agg[(size_t)node * 128 + chunk * 32 + sub] = m0;
}

// ============ update GEMM: h = relu(agg@W_agg + self + b_upd); fused u,v ============
// Register-prefetch pipeline (same pattern as k_gemm): commit regs->LDS,
// barrier, issue next step's loads, compute, barrier.
__global__ __launch_bounds__(256) void k_update2(
    const float* __restrict__ agg, const float* __restrict__ W_agg,
    const float* __restrict__ b_upd, const float* __restrict__ xw,
    const float* __restrict__ W_dec, const float* __restrict__ b_dec,
    float* __restrict__ h, float* __restrict__ u, float* __restrict__ v, int M) {
  __shared__ float AsT[32][33];
  __shared__ float Bs[32][128];
  const int m0 = blockIdx.x * 32;
  const int t = threadIdx.x;
  const int ty = t >> 5, tx = t & 31;
  const int lar = t >> 3, lac = (t & 7) << 2;
  const int arow = m0 + lar;
  const bool avalid = arow < M;
  const int br0 = t >> 5;

  auto loadAgg = [&](int k0) -> float4 {
    float4 av = make_float4(0.f, 0.f, 0.f, 0.f);
    if (avalid) av = *reinterpret_cast<const float4*>(&agg[(size_t)arow * 128 + k0 + lac]);
    return av;
  };

  float4 ra = loadAgg(0);
  float4 rb0 = *reinterpret_cast<const float4*>(&W_agg[(size_t)(br0 + 0) * 128 + tx * 4]);
  float4 rb1 = *reinterpret_cast<const float4*>(&W_agg[(size_t)(br0 + 8) * 128 + tx * 4]);
  float4 rb2 = *reinterpret_cast<const float4*>(&W_agg[(size_t)(br0 + 16) * 128 + tx * 4]);
  float4 rb3 = *reinterpret_cast<const float4*>(&W_agg[(size_t)(br0 + 24) * 128 + tx * 4]);

  float acc[4][4] = {};
  for (int k0 = 0; k0 < 128; k0 += 32) {
    AsT[lac + 0][lar] = ra.x;
    AsT[lac + 1][lar] = ra.y;
    AsT[lac + 2][lar] = ra.z;
    AsT[lac + 3][lar] = ra.w;
    *reinterpret_cast<float4*>(&Bs[br0 + 0][tx * 4]) = rb0;
    *reinterpret_cast<float4*>(&Bs[br0 + 8][tx * 4]) = rb1;
    *reinterpret_cast<float4*>(&Bs[br0 + 16][tx * 4]) = rb2;
    *reinterpret_cast<float4*>(&Bs[br0 + 24][tx * 4]) = rb3;
    __syncthreads();
    const bool more = (k0 + 32) < 128;
    if (more) {
      ra = loadAgg(k0 + 32);
      rb0 = *reinterpret_cast<const float4*>(&W_agg[(size_t)(k0 + 32 + br0 + 0) * 128 + tx * 4]);
      rb1 = *reinterpret_cast<const float4*>(&W_agg[(size_t)(k0 + 32 + br0 + 8) * 128 + tx * 4]);
      rb2 = *reinterpret_cast<const float4*>(&W_agg[(size_t)(k0 + 32 + br0 + 16) * 128 + tx * 4]);
      rb3 = *reinterpret_cast<const float4*>(&W_agg[(size_t)(k0 + 32 + br0 + 24) * 128 + tx * 4]);
    }
#pragma unroll
    for (int k = 0; k < 32; ++k) {
      float4 a4 = *reinterpret_cast<const float4*>(&AsT[k][ty * 4]);
      float4 b4 = *reinterpret_cast<const float4*>(&Bs[k][tx * 4]);
      const float aa[4] = {a4.x, a4.y, a4.z, a4.w};
      const float bb[4] = {b4.x, b4.y, b4.z, b4.w};
#pragma unroll
      for (int j = 0; j < 4; ++j)
#pragma unroll
        for (int c = 0; c < 4; ++c) acc[j][c] = fmaf(aa[j], bb[c], acc[j][c]);
    }
    __syncthreads();
  }
  const float4 bu4 = *reinterpret_cast<const float4*>(&b_upd[tx * 4]);
  const float4 wdu = *reinterpret_cast<const float4*>(&W_dec[tx * 4]);
  const float4 wdv = *reinterpret_cast<const float4*>(&W_dec[128 + tx * 4]);
  const float bd = b_dec[0];
#pragma unroll
  for (int j = 0; j < 4; ++j) {
    int row = m0 + ty * 4 + j;
    if (row >= M) continue;
    float4 sf = *reinterpret_cast<const float4*>(&xw[(size_t)row * 256 + 128 + tx * 4]);
    float4 h4;
    h4.x = fmaxf(acc[j][0] + sf.x + bu4.x, 0.f);
    h4.y = fmaxf(acc[j][1] + sf.y + bu4.y, 0.f);
    h4.z = fmaxf(acc[j][2] + sf.z + bu4.z, 0.f);
    h4.w = fmaxf(acc[j][3] + sf.w + bu4.w, 0.f);
    *reinterpret_cast<float4*>(&h[(size_t)row * 128 + tx * 4]) = h4;
    float up = h4.x * wdu.x + h4.y * wdu.y + h4.z * wdu.z + h4.w * wdu.w;
    float vp = h4.x * wdv.x + h4.y * wdv.y + h4.z * wdv.z + h4.w * wdv.w;
#pragma unroll
    for (int m = 16; m > 0; m >>= 1) {
      up += __shfl_xor(up, m);
      vp += __shfl_xor(vp, m);
    }
    if (tx == 0) {
      u[row] = up + bd;
      v[row] = vp;
    }
  }
}

// ============ fused losses: edge BCE partials + node y/max + y-BCE partials ============
#define GB 512
__global__ __launch_bounds__(256) void k_losses(
    const int* __restrict__ src, const int* __restrict__ dst, const float* __restrict__ u,
    const float* __restrict__ v, const int* __restrict__ tgt, const int* __restrict__ row_ptr,
    const int* __restrict__ csr_src, const int* __restrict__ row_ptr2,
    const int* __restrict__ csr_dst, const int* __restrict__ reach_row,
    float* __restrict__ ybuf, float* __restrict__ yout, int write_out,
    double* __restrict__ pe_slot, double* __restrict__ py_slot, int E, int N) {
  __shared__ double wsum[4];
  double term = 0.0;
  for (int e = blockIdx.x * blockDim.x + threadIdx.x; e < E; e += GB * 256) {
    float l = u[src[e]] + v[dst[e]];
    float xsel = (tgt[e] != 0) ? -l : l;
    float sp = log1pf(expf(xsel));
    term += (double)fmaxf(-sp, -100.0f);
  }
#pragma unroll
  for (int off = 32; off > 0; off >>= 1) term += __shfl_down(term, off);
  if ((threadIdx.x & 63) == 0) wsum[threadIdx.x >> 6] = term;
  __syncthreads();
  if (threadIdx.x == 0) pe_slot[blockIdx.x] = wsum[0] + wsum[1] + wsum[2] + wsum[3];
  __syncthreads();
  double c = 0.0;
  for (int n = blockIdx.x * blockDim.x + threadIdx.x; n < N; n += GB * 256) {
    float mu = -INFINITY, mv = -INFINITY;
    // incoming-u max, 4 gathers in flight
    {
      const int b1 = row_ptr[n], e1 = row_ptr[n + 1];
      int i = b1;
      float a0 = -INFINITY, a1 = -INFINITY, a2 = -INFINITY, a3 = -INFINITY;
      for (; i + 3 < e1; i += 4) {
        int s0 = csr_src[i], s1 = csr_src[i + 1], s2 = csr_src[i + 2], s3 = csr_src[i + 3];
        float u0 = u[s0], u1 = u[s1], u2 = u[s2], u3 = u[s3];
        a0 = fmaxf(a0, u0); a1 = fmaxf(a1, u1);
        a2 = fmaxf(a2, u2); a3 = fmaxf(a3, u3);
      }
      for (; i < e1; ++i) a0 = fmaxf(a0, u[csr_src[i]]);
      mu = fmaxf(fmaxf(a0, a1), fmaxf(a2, a3));
    }
    // outgoing-v max, 4 gathers in flight
    {
      const int b2 = row_ptr2[n], e2 = row_ptr2[n + 1];
      int i = b2;
      float a0 = -INFINITY, a1 = -INFINITY, a2 = -INFINITY, a3 = -INFINITY;
      for (; i + 3 < e2; i += 4) {
        int d0 = csr_dst[i], d1 = csr_dst[i + 1], d2 = csr_dst[i + 2], d3 = csr_dst[i + 3];
        float v0 = v[d0], v1 = v[d1], v2 = v[d2], v3 = v[d3];
        a0 = fmaxf(a0, v0); a1 = fmaxf(a1, v1);
        a2 = fmaxf(a2, v2); a3 = fmaxf(a3, v3);
      }
      for (; i < e2; ++i) a0 = fmaxf(a0, v[csr_dst[i]]);
      mv = fmaxf(fmaxf(a0, a1), fmaxf(a2, a3));
    }
    float m = fmaxf(mu + v[n], u[n] + mv);
    float a = 1.0f / (1.0f + expf(-m));
    float yv = (a >= 0.8f) ? 1.0f : 0.0f;
    ybuf[n] = yv;
    if (write_out) yout[n] = yv;
    if ((float)reach_row[n] != yv) c = 100.0;
  }
#pragma unroll
  for (int off = 32; off > 0; off >>= 1) c += __shfl_down(c, off);
  if ((threadIdx.x & 63) == 0) wsum[threadIdx.x >> 6] = c;
  __syncthreads();
  if (threadIdx.x == 0) py_slot[blockIdx.x] = wsum[0] + wsum[1] + wsum[2] + wsum[3];
}

__global__ void k_final(const double* __restrict__ pe, const double* __restrict__ py,
                        float* __restrict__ out4, int N, int E, int T) {
  __shared__ double le[8], ly[8];
  int lane = threadIdx.x;  // 64 threads
  for (int it = 0; it < T; ++it) {
    double s = 0.0;
    for (int i = lane; i < GB; i += 64) s += pe[(size_t)it * GB + i];
#pragma unroll
    for (int off = 32; off > 0; off >>= 1) s += __shfl_down(s, off);
    if (lane == 0) le[it] = s;
    double s2 = 0.0;
    for (int i = lane; i < GB; i += 64) s2 += py[(size_t)it * GB + i];
#pragma unroll
    for (int off = 32; off > 0; off >>= 1) s2 += __shfl_down(s2, off);
    if (lane == 0) ly[it] = s2;
  }
  __syncthreads();
  if (lane == 0) {
    float loss_x = (float)(-le[T - 1] / (double)E);
    float loss_h = 0.0f;
    for (int i = 0; i < T - 1; ++i) loss_h += (float)(-le[i] / (double)E);
    float yl_x = (float)(ly[T - 1] / (double)N);
    float yl_h = 0.0f;
    for (int i = 0; i < T - 1; ++i) yl_h += (float)(ly[i] / (double)N);
    out4[0] = loss_x;
    out4[1] = loss_h;
    out4[2] = yl_x;
    out4[3] = yl_h;
  }
}

// ============ launch ============
extern "C" void kernel_launch(void* const* d_in, const int* in_sizes, int n_in,
                              void* d_out, int out_size, void* d_ws, size_t ws_size,
                              hipStream_t stream) {
  const float* pos = (const float*)d_in[0];
  const float* s = (const float*)d_in[1];
  const int* eidx = (const int*)d_in[2];
  const int* pi = (const int*)d_in[3];
  const int* pi_h = (const int*)d_in[4];
  const int* reach = (const int*)d_in[5];
  const float* W_enc = (const float*)d_in[6];
  const float* b_enc = (const float*)d_in[7];
  const float* W_msg = (const float*)d_in[8];
  const float* b_msg = (const float*)d_in[9];
  const float* W_self = (const float*)d_in[10];
  const float* W_agg = (const float*)d_in[11];
  const float* b_upd = (const float*)d_in[12];
  const float* W_dec = (const float*)d_in[13];
  const float* b_dec = (const float*)d_in[14];

  const int N = in_sizes[0];
  const int E = in_sizes[3];
  const int T = in_sizes[4] / in_sizes[3];
  const int* src = eidx;
  const int* dst = eidx + E;

  char* w = (char*)d_ws;
  auto alloc = [&](size_t bytes) {
    char* p = w;
    w += (bytes + 255) & ~(size_t)255;
    return p;
  };
  float* xw = (float*)alloc((size_t)N * 256 * 4);
  float* agg = (float*)alloc((size_t)N * 128 * 4);
  float* h = (float*)alloc((size_t)N * 128 * 4);
  float* Wcat = (float*)alloc(256 * 256 * 4);
  float* bcat = (float*)alloc(256 * 4);
  float* u = (float*)alloc((size_t)N * 4);
  float* v = (float*)alloc((size_t)N * 4);
  float* ybuf = (float*)alloc((size_t)N * 4);
  int* cnt_d = (int*)alloc((size_t)N * 4);
  int* cnt_s = (int*)alloc((size_t)N * 4);
  int* row_ptr = (int*)alloc((size_t)(N + 1) * 4);
  int* row_ptr2 = (int*)alloc((size_t)(N + 1) * 4);
  int* csr_src = (int*)alloc((size_t)E * 4);
  int* csr_dst = (int*)alloc((size_t)E * 4);
  int* partial_d = (int*)alloc((size_t)CSR_B * N * 4);
  int* partial_s = (int*)alloc((size_t)CSR_B * N * 4);
  double* pe = (double*)alloc((size_t)T * GB * 8);
  double* py = (double*)alloc((size_t)T * GB * 8);
  const int NB2 = (N + SCAN_CHUNK - 1) / SCAN_CHUNK;
  int* bsum = (int*)alloc((size_t)2 * NB2 * 4);

  float* outy = (float*)d_out;
  float* out4 = outy + N;

  k_build_w<<<256, 256, 0, stream>>>(W_msg, W_self, b_msg, Wcat, bcat);

  const size_t lds2 = (size_t)2 * ((N + 1) >> 1) * 4;  // ~80 KB
  k_hist2<<<CSR_B, 512, lds2, stream>>>(eidx, E, N, partial_d, partial_s);
  k_colscan2<<<(2 * N + 255) / 256, 256, 0, stream>>>(partial_d, cnt_d, partial_s, cnt_s, N);
  k_bsum<<<dim3(NB2, 2), 256, 0, stream>>>(cnt_d, cnt_s, bsum, N, NB2);
  k_bscan<<<1, 64, 0, stream>>>(bsum, NB2);
  k_scanf<<<dim3(NB2, 2), 256, 0, stream>>>(cnt_d, cnt_s, bsum, row_ptr, row_ptr2, N, NB2);
  k_scatter2<<<CSR_B, 512, lds2, stream>>>(eidx, E, N, partial_d, row_ptr, csr_src, partial_s,
                                           row_ptr2, csr_dst);

  const int Nh = (N + 1) / 2;
  const int NB = (Nh + 7) / 8;

  const float* sfeat = s;
  for (int it = 0; it < T; ++it) {
    dim3 g1((N + 63) / 64, 2);
    if (it == 0)
      k_gemm<true><<<g1, 256, 0, stream>>>(pos, sfeat, h, W_enc, b_enc, Wcat, bcat, xw, N);
    else
      k_gemm<false><<<g1, 256, 0, stream>>>(pos, sfeat, h, W_enc, b_enc, Wcat, bcat, xw, N);

    k_aggmax<<<dim3(8, NB), 256, 0, stream>>>(xw, row_ptr, csr_src, agg, N, Nh);

    k_update2<<<(N + 31) / 32, 256, 0, stream>>>(agg, W_agg, b_upd, xw, W_dec, b_dec,
                                                 h, u, v, N);

    const int* tgt = (it < T - 1) ? (pi_h + (size_t)(it + 1) * E) : pi;
    const int* rrow = (it < T - 1) ? (reach + (size_t)(it + 1) * N) : (reach + (size_t)(T - 1) * N);
    k_losses<<<GB, 256, 0, stream>>>(src, dst, u, v, tgt, row_ptr, csr_src, row_ptr2, csr_dst,
                                     rrow, ybuf, outy, (it == T - 1) ? 1 : 0,
                                     pe + (size_t)it * GB, py + (size_t)it * GB, E, N);
    sfeat = ybuf;
  }
  k_final<<<1, 64, 0, stream>>>(pe, py, out4, N, E, T);
}

// Round 21
// 465.038 us; speedup vs baseline: 1.1219x; 1.0055x over previous
//
#include <hip/hip_runtime.h>

// ============ CSR build (both directions, one pass, no global atomics) ============
#define CSR_B 128

__global__ __launch_bounds__(512) void k_hist2(const int* __restrict__ eidx, int E, int N,
                                               int* __restrict__ partial_d,
                                               int* __restrict__ partial_s) {
  extern __shared__ unsigned int hist[];  // [2*nw]
  int nw = (N + 1) >> 1;
  for (int i = threadIdx.x; i < 2 * nw; i += blockDim.x) hist[i] = 0u;
  __syncthreads();
  const int* src = eidx;
  const int* dst = eidx + E;
  int chunk = (E + CSR_B - 1) / CSR_B;
  int beg = blockIdx.x * chunk, end = min(E, beg + chunk);
  for (int e = beg + threadIdx.x; e < end; e += blockDim.x) {
    int d = dst[e];
    atomicAdd(&hist[d >> 1], 1u << ((d & 1) * 16));
    int s = src[e];
    atomicAdd(&hist[nw + (s >> 1)], 1u << ((s & 1) * 16));
  }
  __syncthreads();
  for (int i = threadIdx.x; i < N; i += blockDim.x) {
    partial_d[(size_t)blockIdx.x * N + i] = (int)((hist[i >> 1] >> ((i & 1) * 16)) & 0xFFFFu);
    partial_s[(size_t)blockIdx.x * N + i] = (int)((hist[nw + (i >> 1)] >> ((i & 1) * 16)) & 0xFFFFu);
  }
}

__global__ __launch_bounds__(256) void k_colscan2(int* __restrict__ partial_d,
                                                  int* __restrict__ cnt_d,
                                                  int* __restrict__ partial_s,
                                                  int* __restrict__ cnt_s, int N) {
  int g = blockIdx.x * blockDim.x + threadIdx.x;
  int* partial;
  int* cnt;
  int bin;
  if (g < N) { partial = partial_d; cnt = cnt_d; bin = g; }
  else if (g < 2 * N) { partial = partial_s; cnt = cnt_s; bin = g - N; }
  else return;
  int run = 0;
  for (int b = 0; b < CSR_B; ++b) {
    int t = partial[(size_t)b * N + bin];
    partial[(size_t)b * N + bin] = run;
    run += t;
  }
  cnt[bin] = run;
}

// ============ hierarchical scan ============
#define SCAN_CHUNK 2048

__global__ __launch_bounds__(256) void k_bsum(const int* __restrict__ cnt_d,
                                              const int* __restrict__ cnt_s,
                                              int* __restrict__ bsum, int N, int NB2) {
  const int* cnt = blockIdx.y ? cnt_s : cnt_d;
  int base = blockIdx.x * SCAN_CHUNK;
  int hi = min(N, base + SCAN_CHUNK);
  int s = 0;
  for (int i = base + threadIdx.x; i < hi; i += 256) s += cnt[i];
#pragma unroll
  for (int off = 32; off > 0; off >>= 1) s += __shfl_down(s, off);
  __shared__ int ws[4];
  if ((threadIdx.x & 63) == 0) ws[threadIdx.x >> 6] = s;
  __syncthreads();
  if (threadIdx.x == 0) bsum[blockIdx.y * NB2 + blockIdx.x] = ws[0] + ws[1] + ws[2] + ws[3];
}

__global__ void k_bscan(int* __restrict__ bsum, int NB2) {
  if (threadIdx.x < 2) {
    int* b = bsum + threadIdx.x * NB2;
    int run = 0;
    for (int i = 0; i < NB2; ++i) {
      int t = b[i];
      b[i] = run;
      run += t;
    }
  }
}

__global__ __launch_bounds__(256) void k_scanf(const int* __restrict__ cnt_d,
                                               const int* __restrict__ cnt_s,
                                               const int* __restrict__ bsum,
                                               int* __restrict__ rp_d, int* __restrict__ rp_s,
                                               int N, int NB2) {
  const int* cnt = blockIdx.y ? cnt_s : cnt_d;
  int* rp = blockIdx.y ? rp_s : rp_d;
  const int t = threadIdx.x;
  const int idx0 = blockIdx.x * SCAN_CHUNK + t * 8;
  int vals[8];
  int s = 0;
#pragma unroll
  for (int j = 0; j < 8; ++j) {
    int i = idx0 + j;
    int v = (i < N) ? cnt[i] : 0;
    vals[j] = v;
    s += v;
  }
  __shared__ int sums[256];
  sums[t] = s;
  __syncthreads();
  for (int off = 1; off < 256; off <<= 1) {
    int v = (t >= off) ? sums[t - off] : 0;
    __syncthreads();
    sums[t] += v;
    __syncthreads();
  }
  int run = bsum[blockIdx.y * NB2 + blockIdx.x] + ((t > 0) ? sums[t - 1] : 0);
#pragma unroll
  for (int j = 0; j < 8; ++j) {
    int i = idx0 + j;
    if (i < N) {
      run += vals[j];
      rp[i + 1] = run;
    }
  }
  if (t == 0 && blockIdx.x == 0) rp[0] = 0;
}

__global__ __launch_bounds__(512) void k_scatter2(
    const int* __restrict__ eidx, int E, int N,
    const int* __restrict__ partial_d, const int* __restrict__ rp_d, int* __restrict__ csr_src,
    const int* __restrict__ partial_s, const int* __restrict__ rp_s, int* __restrict__ csr_dst) {
  extern __shared__ unsigned int cur[];  // [2*nw]
  int nw = (N + 1) >> 1;
  for (int i = threadIdx.x; i < 2 * nw; i += blockDim.x) cur[i] = 0u;
  __syncthreads();
  const int* src = eidx;
  const int* dst = eidx + E;
  int chunk = (E + CSR_B - 1) / CSR_B;
  int beg = blockIdx.x * chunk, end = min(E, beg + chunk);
  for (int e = beg + threadIdx.x; e < end; e += blockDim.x) {
    int d = dst[e], s = src[e];
    int shd = (d & 1) * 16;
    unsigned int old = atomicAdd(&cur[d >> 1], 1u << shd);
    csr_src[rp_d[d] + partial_d[(size_t)blockIdx.x * N + d] + (int)((old >> shd) & 0xFFFFu)] = s;
    int shs = (s & 1) * 16;
    unsigned int old2 = atomicAdd(&cur[nw + (s >> 1)], 1u << shs);
    csr_dst[rp_s[s] + partial_s[(size_t)blockIdx.x * N + s] + (int)((old2 >> shs) & 0xFFFFu)] = d;
  }
}

// ============ weights prep ============
__global__ void k_build_w(const float* __restrict__ W_msg, const float* __restrict__ W_self,
                          const float* __restrict__ b_msg, float* __restrict__ Wcat,
                          float* __restrict__ bcat) {
  int idx = blockIdx.x * blockDim.x + threadIdx.x;  // 256*256
  int k = idx >> 8, j = idx & 255;
  Wcat[idx] = (j < 128) ? W_msg[k * 128 + j] : W_self[k * 128 + (j - 128)];
  if (idx < 256) bcat[idx] = (idx < 128) ? b_msg[idx] : 0.0f;
}

// ============ GEMM: xw[M,256] = x[M,256] @ Wcat + bcat ============
// BM=64, BN=128, BK=32, 256 thr, 4 rows x 8 cols/thread + register-prefetch
// (commit regs->LDS, barrier, issue next loads, compute, barrier). BK=32
// halves barrier count vs BK=16 (8 steps for K=256).
// NOTE: single-buffered on purpose — explicit LDS dbuf raises VGPR 48->128
// and regresses (measured twice, R4/R15).
__device__ __forceinline__ float4 enc4(float p, float sf, float4 we0, float4 we1, float4 be) {
  float4 r;
  r.x = fmaxf(fmaf(p, we0.x, fmaf(sf, we1.x, be.x)), 0.f);
  r.y = fmaxf(fmaf(p, we0.y, fmaf(sf, we1.y, be.y)), 0.f);
  r.z = fmaxf(fmaf(p, we0.z, fmaf(sf, we1.z, be.z)), 0.f);
  r.w = fmaxf(fmaf(p, we0.w, fmaf(sf, we1.w, be.w)), 0.f);
  return r;
}

template <bool IT0>
__global__ __launch_bounds__(256) void k_gemm(
    const float* __restrict__ pos, const float* __restrict__ sfeat,
    const float* __restrict__ hsrc, const float* __restrict__ W_enc,
    const float* __restrict__ b_enc, const float* __restrict__ B,
    const float* __restrict__ bias, float* __restrict__ C, int M) {
  __shared__ float As[32][68];    // [k][row], +4 pad
  __shared__ float Bs[32][132];   // [k][col], +4 pad
  const int m0 = blockIdx.x * 64, n0 = blockIdx.y * 128;
  const int t = threadIdx.x;
  const int ty = t >> 4;          // [0,16): rows ty*4..ty*4+3
  const int tx = t & 15;          // [0,16): cols tx*4 and 64+tx*4
  const int lr = t >> 2, lq = (t & 3) << 2;  // A-load: row [0,64), quads lq and lq+16
  const int row_ld = m0 + lr;
  const bool valid = row_ld < M;
  float p = 0.f, sf = 0.f;
  if (valid) { p = pos[row_ld]; sf = sfeat[row_ld]; }
  const int bk0 = t >> 5, bc0 = (t & 31) << 2;  // B-load: rows bk0 + 8q
  const int KMAX = IT0 ? 128 : 256;

  auto loadA = [&](int k0, int off) -> float4 {
    float4 av = make_float4(0.f, 0.f, 0.f, 0.f);
    const int col = k0 + lq + off;
    if (valid) {
      if (col < 128) {
        float4 we0 = *reinterpret_cast<const float4*>(&W_enc[col]);
        float4 we1 = *reinterpret_cast<const float4*>(&W_enc[128 + col]);
        float4 be = *reinterpret_cast<const float4*>(&b_enc[col]);
        av = enc4(p, sf, we0, we1, be);
      } else {
        av = *reinterpret_cast<const float4*>(&hsrc[(size_t)row_ld * 128 + col - 128]);
      }
    }
    return av;
  };
  auto loadB = [&](int k0, int q) -> float4 {
    return *reinterpret_cast<const float4*>(&B[(size_t)(k0 + bk0 + q * 8) * 256 + n0 + bc0]);
  };

  float4 ra0 = loadA(0, 0), ra1 = loadA(0, 16);
  float4 rb0 = loadB(0, 0), rb1 = loadB(0, 1), rb2 = loadB(0, 2), rb3 = loadB(0, 3);

  float acc[4][8] = {};
  for (int k0 = 0; k0 < KMAX; k0 += 32) {
    As[lq + 0][lr] = ra0.x;
    As[lq + 1][lr] = ra0.y;
    As[lq + 2][lr] = ra0.z;
    As[lq + 3][lr] = ra0.w;
    As[lq + 16][lr] = ra1.x;
    As[lq + 17][lr] = ra1.y;
    As[lq + 18][lr] = ra1.z;
    As[lq + 19][lr] = ra1.w;
    *reinterpret_cast<float4*>(&Bs[bk0 + 0][bc0]) = rb0;
    *reinterpret_cast<float4*>(&Bs[bk0 + 8][bc0]) = rb1;
    *reinterpret_cast<float4*>(&Bs[bk0 + 16][bc0]) = rb2;
    *reinterpret_cast<float4*>(&Bs[bk0 + 24][bc0]) = rb3;
    __syncthreads();
    const bool more = (k0 + 32) < KMAX;
    if (more) {
      ra0 = loadA(k0 + 32, 0);
      ra1 = loadA(k0 + 32, 16);
      rb0 = loadB(k0 + 32, 0);
      rb1 = loadB(k0 + 32, 1);
      rb2 = loadB(k0 + 32, 2);
      rb3 = loadB(k0 + 32, 3);
    }
#pragma unroll
    for (int k = 0; k < 32; ++k) {
      float4 a4 = *reinterpret_cast<const float4*>(&As[k][ty * 4]);
      float4 b0 = *reinterpret_cast<const float4*>(&Bs[k][tx * 4]);
      float4 b1 = *reinterpret_cast<const float4*>(&Bs[k][64 + tx * 4]);
      const float a[4] = {a4.x, a4.y, a4.z, a4.w};
      const float bb[8] = {b0.x, b0.y, b0.z, b0.w, b1.x, b1.y, b1.z, b1.w};
#pragma unroll
      for (int i = 0; i < 4; ++i)
#pragma unroll
        for (int j = 0; j < 8; ++j) acc[i][j] = fmaf(a[i], bb[j], acc[i][j]);
    }
    __syncthreads();
  }
  float4 bi0 = *reinterpret_cast<const float4*>(&bias[n0 + tx * 4]);
  float4 bi1 = *reinterpret_cast<const float4*>(&bias[n0 + 64 + tx * 4]);
#pragma unroll
  for (int i = 0; i < 4; ++i) {
    int row = m0 + ty * 4 + i;
    if (row < M) {
      float4 o0 = make_float4(acc[i][0] + bi0.x, acc[i][1] + bi0.y, acc[i][2] + bi0.z,
                              acc[i][3] + bi0.w);
      float4 o1 = make_float4(acc[i][4] + bi1.x, acc[i][5] + bi1.y, acc[i][6] + bi1.z,
                              acc[i][7] + bi1.w);
      *reinterpret_cast<float4*>(&C[(size_t)row * 256 + n0 + tx * 4]) = o0;
      *reinterpret_cast<float4*>(&C[(size_t)row * 256 + n0 + 64 + tx * 4]) = o1;
    }
  }
}

// ============ aggmax: feature-chunked for per-XCD L2 residence, 8-deep MLP ============
__global__ __launch_bounds__(256) void k_aggmax(
    const float* __restrict__ xw, const int* __restrict__ row_ptr,
    const int* __restrict__ csr_src, float* __restrict__ agg, int N, int Nh) {
  const int cx = blockIdx.x & 7;
  const int chunk = cx & 3;
  const int half = cx >> 2;
  const int hw = threadIdx.x >> 5;
  const int sub = threadIdx.x & 31;
  const int node = half * Nh + blockIdx.y * 8 + hw;
  const int hi = half ? N : Nh;
  if (node >= hi) return;
  const float* base = xw + chunk * 32 + sub;
  const int beg = row_ptr[node], end = row_ptr[node + 1];
  float m0 = 0.f, m1 = 0.f, m2 = 0.f, m3 = 0.f;
  float m4 = 0.f, m5 = 0.f, m6 = 0.f, m7 = 0.f;
  int i = beg;
  for (; i + 7 < end; i += 8) {  // 8 independent gathers in flight
    int e0 = csr_src[i + 0], e1 = csr_src[i + 1], e2 = csr_src[i + 2], e3 = csr_src[i + 3];
    int e4 = csr_src[i + 4], e5 = csr_src[i + 5], e6 = csr_src[i + 6], e7 = csr_src[i + 7];
    float f0 = base[(size_t)e0 * 256];
    float f1 = base[(size_t)e1 * 256];
    float f2 = base[(size_t)e2 * 256];
    float f3 = base[(size_t)e3 * 256];
    float f4 = base[(size_t)e4 * 256];
    float f5 = base[(size_t)e5 * 256];
    float f6 = base[(size_t)e6 * 256];
    float f7 = base[(size_t)e7 * 256];
    m0 = fmaxf(m0, f0); m1 = fmaxf(m1, f1);
    m2 = fmaxf(m2, f2); m3 = fmaxf(m3, f3);
    m4 = fmaxf(m4, f4); m5 = fmaxf(m5, f5);
    m6 = fmaxf(m6, f6); m7 = fmaxf(m7, f7);
  }
  for (; i < end; ++i) m0 = fmaxf(m0, base[(size_t)csr_src[i] * 256]);
  m0 = fmaxf(fmaxf(fmaxf(m0, m1), fmaxf(m2, m3)),
             fmaxf(fmaxf(m4, m5), fmaxf(m6, m7)));
  agg[(size_t)node * 128 + chunk * 32 + sub] = m0;
}

// ============ update GEMM: h = relu(agg@W_agg + self + b_upd); fused u,v ============
// Register-prefetch pipeline (same pattern as k_gemm).
__global__ __launch_bounds__(256) void k_update2(
    const float* __restrict__ agg, const float* __restrict__ W_agg,
    const float* __restrict__ b_upd, const float* __restrict__ xw,
    const float* __restrict__ W_dec, const float* __restrict__ b_dec,
    float* __restrict__ h, float* __restrict__ u, float* __restrict__ v, int M) {
  __shared__ float AsT[32][33];
  __shared__ float Bs[32][128];
  const int m0 = blockIdx.x * 32;
  const int t = threadIdx.x;
  const int ty = t >> 5, tx = t & 31;
  const int lar = t >> 3, lac = (t & 7) << 2;
  const int arow = m0 + lar;
  const bool avalid = arow < M;
  const int br0 = t >> 5;

  auto loadAgg = [&](int k0) -> float4 {
    float4 av = make_float4(0.f, 0.f, 0.f, 0.f);
    if (avalid) av = *reinterpret_cast<const float4*>(&agg[(size_t)arow * 128 + k0 + lac]);
    return av;
  };

  float4 ra = loadAgg(0);
  float4 rb0 = *reinterpret_cast<const float4*>(&W_agg[(size_t)(br0 + 0) * 128 + tx * 4]);
  float4 rb1 = *reinterpret_cast<const float4*>(&W_agg[(size_t)(br0 + 8) * 128 + tx * 4]);
  float4 rb2 = *reinterpret_cast<const float4*>(&W_agg[(size_t)(br0 + 16) * 128 + tx * 4]);
  float4 rb3 = *reinterpret_cast<const float4*>(&W_agg[(size_t)(br0 + 24) * 128 + tx * 4]);

  float acc[4][4] = {};
  for (int k0 = 0; k0 < 128; k0 += 32) {
    AsT[lac + 0][lar] = ra.x;
    AsT[lac + 1][lar] = ra.y;
    AsT[lac + 2][lar] = ra.z;
    AsT[lac + 3][lar] = ra.w;
    *reinterpret_cast<float4*>(&Bs[br0 + 0][tx * 4]) = rb0;
    *reinterpret_cast<float4*>(&Bs[br0 + 8][tx * 4]) = rb1;
    *reinterpret_cast<float4*>(&Bs[br0 + 16][tx * 4]) = rb2;
    *reinterpret_cast<float4*>(&Bs[br0 + 24][tx * 4]) = rb3;
    __syncthreads();
    const bool more = (k0 + 32) < 128;
    if (more) {
      ra = loadAgg(k0 + 32);
      rb0 = *reinterpret_cast<const float4*>(&W_agg[(size_t)(k0 + 32 + br0 + 0) * 128 + tx * 4]);
      rb1 = *reinterpret_cast<const float4*>(&W_agg[(size_t)(k0 + 32 + br0 + 8) * 128 + tx * 4]);
      rb2 = *reinterpret_cast<const float4*>(&W_agg[(size_t)(k0 + 32 + br0 + 16) * 128 + tx * 4]);
      rb3 = *reinterpret_cast<const float4*>(&W_agg[(size_t)(k0 + 32 + br0 + 24) * 128 + tx * 4]);
    }
#pragma unroll
    for (int k = 0; k < 32; ++k) {
      float4 a4 = *reinterpret_cast<const float4*>(&AsT[k][ty * 4]);
      float4 b4 = *reinterpret_cast<const float4*>(&Bs[k][tx * 4]);
      const float aa[4] = {a4.x, a4.y, a4.z, a4.w};
      const float bb[4] = {b4.x, b4.y, b4.z, b4.w};
#pragma unroll
      for (int j = 0; j < 4; ++j)
#pragma unroll
        for (int c = 0; c < 4; ++c) acc[j][c] = fmaf(aa[j], bb[c], acc[j][c]);
    }
    __syncthreads();
  }
  const float4 bu4 = *reinterpret_cast<const float4*>(&b_upd[tx * 4]);
  const float4 wdu = *reinterpret_cast<const float4*>(&W_dec[tx * 4]);
  const float4 wdv = *reinterpret_cast<const float4*>(&W_dec[128 + tx * 4]);
  const float bd = b_dec[0];
#pragma unroll
  for (int j = 0; j < 4; ++j) {
    int row = m0 + ty * 4 + j;
    if (row >= M) continue;
    float4 sf = *reinterpret_cast<const float4*>(&xw[(size_t)row * 256 + 128 + tx * 4]);
    float4 h4;
    h4.x = fmaxf(acc[j][0] + sf.x + bu4.x, 0.f);
    h4.y = fmaxf(acc[j][1] + sf.y + bu4.y, 0.f);
    h4.z = fmaxf(acc[j][2] + sf.z + bu4.z, 0.f);
    h4.w = fmaxf(acc[j][3] + sf.w + bu4.w, 0.f);
    *reinterpret_cast<float4*>(&h[(size_t)row * 128 + tx * 4]) = h4;
    float up = h4.x * wdu.x + h4.y * wdu.y + h4.z * wdu.z + h4.w * wdu.w;
    float vp = h4.x * wdv.x + h4.y * wdv.y + h4.z * wdv.z + h4.w * wdv.w;
#pragma unroll
    for (int m = 16; m > 0; m >>= 1) {
      up += __shfl_xor(up, m);
      vp += __shfl_xor(vp, m);
    }
    if (tx == 0) {
      u[row] = up + bd;
      v[row] = vp;
    }
  }
}

// ============ fused losses: edge BCE partials + node y/max + y-BCE partials ============
#define GB 512
__global__ __launch_bounds__(256) void k_losses(
    const int* __restrict__ src, const int* __restrict__ dst, const float* __restrict__ u,
    const float* __restrict__ v, const int* __restrict__ tgt, const int* __restrict__ row_ptr,
    const int* __restrict__ csr_src, const int* __restrict__ row_ptr2,
    const int* __restrict__ csr_dst, const int* __restrict__ reach_row,
    float* __restrict__ ybuf, float* __restrict__ yout, int write_out,
    double* __restrict__ pe_slot, double* __restrict__ py_slot, int E, int N) {
  __shared__ double wsum[4];
  double term = 0.0;
  for (int e = blockIdx.x * blockDim.x + threadIdx.x; e < E; e += GB * 256) {
    float l = u[src[e]] + v[dst[e]];
    float xsel = (tgt[e] != 0) ? -l : l;
    float sp = log1pf(expf(xsel));
    term += (double)fmaxf(-sp, -100.0f);
  }
#pragma unroll
  for (int off = 32; off > 0; off >>= 1) term += __shfl_down(term, off);
  if ((threadIdx.x & 63) == 0) wsum[threadIdx.x >> 6] = term;
  __syncthreads();
  if (threadIdx.x == 0) pe_slot[blockIdx.x] = wsum[0] + wsum[1] + wsum[2] + wsum[3];
  __syncthreads();
  double c = 0.0;
  for (int n = blockIdx.x * blockDim.x + threadIdx.x; n < N; n += GB * 256) {
    float mu = -INFINITY, mv = -INFINITY;
    // incoming-u max, 4 gathers in flight
    {
      const int b1 = row_ptr[n], e1 = row_ptr[n + 1];
      int i = b1;
      float a0 = -INFINITY, a1 = -INFINITY, a2 = -INFINITY, a3 = -INFINITY;
      for (; i + 3 < e1; i += 4) {
        int s0 = csr_src[i], s1 = csr_src[i + 1], s2 = csr_src[i + 2], s3 = csr_src[i + 3];
        float u0 = u[s0], u1 = u[s1], u2 = u[s2], u3 = u[s3];
        a0 = fmaxf(a0, u0); a1 = fmaxf(a1, u1);
        a2 = fmaxf(a2, u2); a3 = fmaxf(a3, u3);
      }
      for (; i < e1; ++i) a0 = fmaxf(a0, u[csr_src[i]]);
      mu = fmaxf(fmaxf(a0, a1), fmaxf(a2, a3));
    }
    // outgoing-v max, 4 gathers in flight
    {
      const int b2 = row_ptr2[n], e2 = row_ptr2[n + 1];
      int i = b2;
      float a0 = -INFINITY, a1 = -INFINITY, a2 = -INFINITY, a3 = -INFINITY;
      for (; i + 3 < e2; i += 4) {
        int d0 = csr_dst[i], d1 = csr_dst[i + 1], d2 = csr_dst[i + 2], d3 = csr_dst[i + 3];
        float v0 = v[d0], v1 = v[d1], v2 = v[d2], v3 = v[d3];
        a0 = fmaxf(a0, v0); a1 = fmaxf(a1, v1);
        a2 = fmaxf(a2, v2); a3 = fmaxf(a3, v3);
      }
      for (; i < e2; ++i) a0 = fmaxf(a0, v[csr_dst[i]]);
      mv = fmaxf(fmaxf(a0, a1), fmaxf(a2, a3));
    }
    float m = fmaxf(mu + v[n], u[n] + mv);
    float a = 1.0f / (1.0f + expf(-m));
    float yv = (a >= 0.8f) ? 1.0f : 0.0f;
    ybuf[n] = yv;
    if (write_out) yout[n] = yv;
    if ((float)reach_row[n] != yv) c = 100.0;
  }
#pragma unroll
  for (int off = 32; off > 0; off >>= 1) c += __shfl_down(c, off);
  if ((threadIdx.x & 63) == 0) wsum[threadIdx.x >> 6] = c;
  __syncthreads();
  if (threadIdx.x == 0) py_slot[blockIdx.x] = wsum[0] + wsum[1] + wsum[2] + wsum[3];
}

__global__ void k_final(const double* __restrict__ pe, const double* __restrict__ py,
                        float* __restrict__ out4, int N, int E, int T) {
  __shared__ double le[8], ly[8];
  int lane = threadIdx.x;  // 64 threads
  for (int it = 0; it < T; ++it) {
    double s = 0.0;
    for (int i = lane; i < GB; i += 64) s += pe[(size_t)it * GB + i];
#pragma unroll
    for (int off = 32; off > 0; off >>= 1) s += __shfl_down(s, off);
    if (lane == 0) le[it] = s;
    double s2 = 0.0;
    for (int i = lane; i < GB; i += 64) s2 += py[(size_t)it * GB + i];
#pragma unroll
    for (int off = 32; off > 0; off >>= 1) s2 += __shfl_down(s2, off);
    if (lane == 0) ly[it] = s2;
  }
  __syncthreads();
  if (lane == 0) {
    float loss_x = (float)(-le[T - 1] / (double)E);
    float loss_h = 0.0f;
    for (int i = 0; i < T - 1; ++i) loss_h += (float)(-le[i] / (double)E);
    float yl_x = (float)(ly[T - 1] / (double)N);
    float yl_h = 0.0f;
    for (int i = 0; i < T - 1; ++i) yl_h += (float)(ly[i] / (double)N);
    out4[0] = loss_x;
    out4[1] = loss_h;
    out4[2] = yl_x;
    out4[3] = yl_h;
  }
}

// ============ launch ============
extern "C" void kernel_launch(void* const* d_in, const int* in_sizes, int n_in,
                              void* d_out, int out_size, void* d_ws, size_t ws_size,
                              hipStream_t stream) {
  const float* pos = (const float*)d_in[0];
  const float* s = (const float*)d_in[1];
  const int* eidx = (const int*)d_in[2];
  const int* pi = (const int*)d_in[3];
  const int* pi_h = (const int*)d_in[4];
  const int* reach = (const int*)d_in[5];
  const float* W_enc = (const float*)d_in[6];
  const float* b_enc = (const float*)d_in[7];
  const float* W_msg = (const float*)d_in[8];
  const float* b_msg = (const float*)d_in[9];
  const float* W_self = (const float*)d_in[10];
  const float* W_agg = (const float*)d_in[11];
  const float* b_upd = (const float*)d_in[12];
  const float* W_dec = (const float*)d_in[13];
  const float* b_dec = (const float*)d_in[14];

  const int N = in_sizes[0];
  const int E = in_sizes[3];
  const int T = in_sizes[4] / in_sizes[3];
  const int* src = eidx;
  const int* dst = eidx + E;

  char* w = (char*)d_ws;
  auto alloc = [&](size_t bytes) {
    char* p = w;
    w += (bytes + 255) & ~(size_t)255;
    return p;
  };
  float* xw = (float*)alloc((size_t)N * 256 * 4);
  float* agg = (float*)alloc((size_t)N * 128 * 4);
  float* h = (float*)alloc((size_t)N * 128 * 4);
  float* Wcat = (float*)alloc(256 * 256 * 4);
  float* bcat = (float*)alloc(256 * 4);
  float* u = (float*)alloc((size_t)N * 4);
  float* v = (float*)alloc((size_t)N * 4);
  float* ybuf = (float*)alloc((size_t)N * 4);
  int* cnt_d = (int*)alloc((size_t)N * 4);
  int* cnt_s = (int*)alloc((size_t)N * 4);
  int* row_ptr = (int*)alloc((size_t)(N + 1) * 4);
  int* row_ptr2 = (int*)alloc((size_t)(N + 1) * 4);
  int* csr_src = (int*)alloc((size_t)E * 4);
  int* csr_dst = (int*)alloc((size_t)E * 4);
  int* partial_d = (int*)alloc((size_t)CSR_B * N * 4);
  int* partial_s = (int*)alloc((size_t)CSR_B * N * 4);
  double* pe = (double*)alloc((size_t)T * GB * 8);
  double* py = (double*)alloc((size_t)T * GB * 8);
  const int NB2 = (N + SCAN_CHUNK - 1) / SCAN_CHUNK;
  int* bsum = (int*)alloc((size_t)2 * NB2 * 4);

  float* outy = (float*)d_out;
  float* out4 = outy + N;

  k_build_w<<<256, 256, 0, stream>>>(W_msg, W_self, b_msg, Wcat, bcat);

  const size_t lds2 = (size_t)2 * ((N + 1) >> 1) * 4;  // ~80 KB
  k_hist2<<<CSR_B, 512, lds2, stream>>>(eidx, E, N, partial_d, partial_s);
  k_colscan2<<<(2 * N + 255) / 256, 256, 0, stream>>>(partial_d, cnt_d, partial_s, cnt_s, N);
  k_bsum<<<dim3(NB2, 2), 256, 0, stream>>>(cnt_d, cnt_s, bsum, N, NB2);
  k_bscan<<<1, 64, 0, stream>>>(bsum, NB2);
  k_scanf<<<dim3(NB2, 2), 256, 0, stream>>>(cnt_d, cnt_s, bsum, row_ptr, row_ptr2, N, NB2);
  k_scatter2<<<CSR_B, 512, lds2, stream>>>(eidx, E, N, partial_d, row_ptr, csr_src, partial_s,
                                           row_ptr2, csr_dst);

  const int Nh = (N + 1) / 2;
  const int NB = (Nh + 7) / 8;

  const float* sfeat = s;
  for (int it = 0; it < T; ++it) {
    dim3 g1((N + 63) / 64, 2);
    if (it == 0)
      k_gemm<true><<<g1, 256, 0, stream>>>(pos, sfeat, h, W_enc, b_enc, Wcat, bcat, xw, N);
    else
      k_gemm<false><<<g1, 256, 0, stream>>>(pos, sfeat, h, W_enc, b_enc, Wcat, bcat, xw, N);

    k_aggmax<<<dim3(8, NB), 256, 0, stream>>>(xw, row_ptr, csr_src, agg, N, Nh);

    k_update2<<<(N + 31) / 32, 256, 0, stream>>>(agg, W_agg, b_upd, xw, W_dec, b_dec,
                                                 h, u, v, N);

    const int* tgt = (it < T - 1) ? (pi_h + (size_t)(it + 1) * E) : pi;
    const int* rrow = (it < T - 1) ? (reach + (size_t)(it + 1) * N) : (reach + (size_t)(T - 1) * N);
    k_losses<<<GB, 256, 0, stream>>>(src, dst, u, v, tgt, row_ptr, csr_src, row_ptr2, csr_dst,
                                     rrow, ybuf, outy, (it == T - 1) ? 1 : 0,
                                     pe + (size_t)it * GB, py + (size_t)it * GB, E, N);
    sfeat = ybuf;
  }
  k_final<<<1, 64, 0, stream>>>(pe, py, out4, N, E, T);
}

// Round 22
// 462.481 us; speedup vs baseline: 1.1281x; 1.0055x over previous
//
#include <hip/hip_runtime.h>

// ============ CSR build (both directions, one pass, no global atomics) ============
// partial counts stored as u16: per-(block,bin) count <= E/CSR_B = 3125 and
// per-column prefix <= node degree (<1000 here) — same bound the packed LDS
// histogram already assumes. Halves partial traffic (82 -> 41 MB).
#define CSR_B 128

__global__ __launch_bounds__(512) void k_hist2(const int* __restrict__ eidx, int E, int N,
                                               unsigned short* __restrict__ partial_d,
                                               unsigned short* __restrict__ partial_s) {
  extern __shared__ unsigned int hist[];  // [2*nw]
  int nw = (N + 1) >> 1;
  for (int i = threadIdx.x; i < 2 * nw; i += blockDim.x) hist[i] = 0u;
  __syncthreads();
  const int* src = eidx;
  const int* dst = eidx + E;
  int chunk = (E + CSR_B - 1) / CSR_B;
  int beg = blockIdx.x * chunk, end = min(E, beg + chunk);
  for (int e = beg + threadIdx.x; e < end; e += blockDim.x) {
    int d = dst[e];
    atomicAdd(&hist[d >> 1], 1u << ((d & 1) * 16));
    int s = src[e];
    atomicAdd(&hist[nw + (s >> 1)], 1u << ((s & 1) * 16));
  }
  __syncthreads();
  for (int i = threadIdx.x; i < N; i += blockDim.x) {
    partial_d[(size_t)blockIdx.x * N + i] =
        (unsigned short)((hist[i >> 1] >> ((i & 1) * 16)) & 0xFFFFu);
    partial_s[(size_t)blockIdx.x * N + i] =
        (unsigned short)((hist[nw + (i >> 1)] >> ((i & 1) * 16)) & 0xFFFFu);
  }
}

__global__ __launch_bounds__(256) void k_colscan2(unsigned short* __restrict__ partial_d,
                                                  int* __restrict__ cnt_d,
                                                  unsigned short* __restrict__ partial_s,
                                                  int* __restrict__ cnt_s, int N) {
  int g = blockIdx.x * blockDim.x + threadIdx.x;
  unsigned short* partial;
  int* cnt;
  int bin;
  if (g < N) { partial = partial_d; cnt = cnt_d; bin = g; }
  else if (g < 2 * N) { partial = partial_s; cnt = cnt_s; bin = g - N; }
  else return;
  int run = 0;
  for (int b = 0; b < CSR_B; ++b) {
    int t = partial[(size_t)b * N + bin];
    partial[(size_t)b * N + bin] = (unsigned short)run;
    run += t;
  }
  cnt[bin] = run;
}

// ============ hierarchical scan ============
#define SCAN_CHUNK 2048

__global__ __launch_bounds__(256) void k_bsum(const int* __restrict__ cnt_d,
                                              const int* __restrict__ cnt_s,
                                              int* __restrict__ bsum, int N, int NB2) {
  const int* cnt = blockIdx.y ? cnt_s : cnt_d;
  int base = blockIdx.x * SCAN_CHUNK;
  int hi = min(N, base + SCAN_CHUNK);
  int s = 0;
  for (int i = base + threadIdx.x; i < hi; i += 256) s += cnt[i];
#pragma unroll
  for (int off = 32; off > 0; off >>= 1) s += __shfl_down(s, off);
  __shared__ int ws[4];
  if ((threadIdx.x & 63) == 0) ws[threadIdx.x >> 6] = s;
  __syncthreads();
  if (threadIdx.x == 0) bsum[blockIdx.y * NB2 + blockIdx.x] = ws[0] + ws[1] + ws[2] + ws[3];
}

__global__ void k_bscan(int* __restrict__ bsum, int NB2) {
  if (threadIdx.x < 2) {
    int* b = bsum + threadIdx.x * NB2;
    int run = 0;
    for (int i = 0; i < NB2; ++i) {
      int t = b[i];
      b[i] = run;
      run += t;
    }
  }
}

__global__ __launch_bounds__(256) void k_scanf(const int* __restrict__ cnt_d,
                                               const int* __restrict__ cnt_s,
                                               const int* __restrict__ bsum,
                                               int* __restrict__ rp_d, int* __restrict__ rp_s,
                                               int N, int NB2) {
  const int* cnt = blockIdx.y ? cnt_s : cnt_d;
  int* rp = blockIdx.y ? rp_s : rp_d;
  const int t = threadIdx.x;
  const int idx0 = blockIdx.x * SCAN_CHUNK + t * 8;
  int vals[8];
  int s = 0;
#pragma unroll
  for (int j = 0; j < 8; ++j) {
    int i = idx0 + j;
    int v = (i < N) ? cnt[i] : 0;
    vals[j] = v;
    s += v;
  }
  __shared__ int sums[256];
  sums[t] = s;
  __syncthreads();
  for (int off = 1; off < 256; off <<= 1) {
    int v = (t >= off) ? sums[t - off] : 0;
    __syncthreads();
    sums[t] += v;
    __syncthreads();
  }
  int run = bsum[blockIdx.y * NB2 + blockIdx.x] + ((t > 0) ? sums[t - 1] : 0);
#pragma unroll
  for (int j = 0; j < 8; ++j) {
    int i = idx0 + j;
    if (i < N) {
      run += vals[j];
      rp[i + 1] = run;
    }
  }
  if (t == 0 && blockIdx.x == 0) rp[0] = 0;
}

__global__ __launch_bounds__(512) void k_scatter2(
    const int* __restrict__ eidx, int E, int N,
    const unsigned short* __restrict__ partial_d, const int* __restrict__ rp_d,
    int* __restrict__ csr_src,
    const unsigned short* __restrict__ partial_s, const int* __restrict__ rp_s,
    int* __restrict__ csr_dst) {
  extern __shared__ unsigned int cur[];  // [2*nw]
  int nw = (N + 1) >> 1;
  for (int i = threadIdx.x; i < 2 * nw; i += blockDim.x) cur[i] = 0u;
  __syncthreads();
  const int* src = eidx;
  const int* dst = eidx + E;
  int chunk = (E + CSR_B - 1) / CSR_B;
  int beg = blockIdx.x * chunk, end = min(E, beg + chunk);
  for (int e = beg + threadIdx.x; e < end; e += blockDim.x) {
    int d = dst[e], s = src[e];
    int shd = (d & 1) * 16;
    unsigned int old = atomicAdd(&cur[d >> 1], 1u << shd);
    csr_src[rp_d[d] + (int)partial_d[(size_t)blockIdx.x * N + d] +
            (int)((old >> shd) & 0xFFFFu)] = s;
    int shs = (s & 1) * 16;
    unsigned int old2 = atomicAdd(&cur[nw + (s >> 1)], 1u << shs);
    csr_dst[rp_s[s] + (int)partial_s[(size_t)blockIdx.x * N + s] +
            (int)((old2 >> shs) & 0xFFFFu)] = d;
  }
}

// ============ weights prep ============
__global__ void k_build_w(const float* __restrict__ W_msg, const float* __restrict__ W_self,
                          const float* __restrict__ b_msg, float* __restrict__ Wcat,
                          float* __restrict__ bcat) {
  int idx = blockIdx.x * blockDim.x + threadIdx.x;  // 256*256
  int k = idx >> 8, j = idx & 255;
  Wcat[idx] = (j < 128) ? W_msg[k * 128 + j] : W_self[k * 128 + (j - 128)];
  if (idx < 256) bcat[idx] = (idx < 128) ? b_msg[idx] : 0.0f;
}

// ============ GEMM: xw[M,256] = x[M,256] @ Wcat + bcat ============
// BM=64, BN=128, BK=32, 256 thr, 4 rows x 8 cols/thread + register-prefetch
// (commit regs->LDS, barrier, issue next loads, compute, barrier).
// NOTE: single-buffered on purpose — explicit LDS dbuf raises VGPR 48->128
// and regresses (measured twice, R4/R15).
__device__ __forceinline__ float4 enc4(float p, float sf, float4 we0, float4 we1, float4 be) {
  float4 r;
  r.x = fmaxf(fmaf(p, we0.x, fmaf(sf, we1.x, be.x)), 0.f);
  r.y = fmaxf(fmaf(p, we0.y, fmaf(sf, we1.y, be.y)), 0.f);
  r.z = fmaxf(fmaf(p, we0.z, fmaf(sf, we1.z, be.z)), 0.f);
  r.w = fmaxf(fmaf(p, we0.w, fmaf(sf, we1.w, be.w)), 0.f);
  return r;
}

template <bool IT0>
__global__ __launch_bounds__(256) void k_gemm(
    const float* __restrict__ pos, const float* __restrict__ sfeat,
    const float* __restrict__ hsrc, const float* __restrict__ W_enc,
    const float* __restrict__ b_enc, const float* __restrict__ B,
    const float* __restrict__ bias, float* __restrict__ C, int M) {
  __shared__ float As[32][68];    // [k][row], +4 pad
  __shared__ float Bs[32][132];   // [k][col], +4 pad
  const int m0 = blockIdx.x * 64, n0 = blockIdx.y * 128;
  const int t = threadIdx.x;
  const int ty = t >> 4;          // [0,16): rows ty*4..ty*4+3
  const int tx = t & 15;          // [0,16): cols tx*4 and 64+tx*4
  const int lr = t >> 2, lq = (t & 3) << 2;  // A-load: row [0,64), quads lq and lq+16
  const int row_ld = m0 + lr;
  const bool valid = row_ld < M;
  float p = 0.f, sf = 0.f;
  if (valid) { p = pos[row_ld]; sf = sfeat[row_ld]; }
  const int bk0 = t >> 5, bc0 = (t & 31) << 2;  // B-load: rows bk0 + 8q
  const int KMAX = IT0 ? 128 : 256;

  auto loadA = [&](int k0, int off) -> float4 {
    float4 av = make_float4(0.f, 0.f, 0.f, 0.f);
    const int col = k0 + lq + off;
    if (valid) {
      if (col < 128) {
        float4 we0 = *reinterpret_cast<const float4*>(&W_enc[col]);
        float4 we1 = *reinterpret_cast<const float4*>(&W_enc[128 + col]);
        float4 be = *reinterpret_cast<const float4*>(&b_enc[col]);
        av = enc4(p, sf, we0, we1, be);
      } else {
        av = *reinterpret_cast<const float4*>(&hsrc[(size_t)row_ld * 128 + col - 128]);
      }
    }
    return av;
  };
  auto loadB = [&](int k0, int q) -> float4 {
    return *reinterpret_cast<const float4*>(&B[(size_t)(k0 + bk0 + q * 8) * 256 + n0 + bc0]);
  };

  float4 ra0 = loadA(0, 0), ra1 = loadA(0, 16);
  float4 rb0 = loadB(0, 0), rb1 = loadB(0, 1), rb2 = loadB(0, 2), rb3 = loadB(0, 3);

  float acc[4][8] = {};
  for (int k0 = 0; k0 < KMAX; k0 += 32) {
    As[lq + 0][lr] = ra0.x;
    As[lq + 1][lr] = ra0.y;
    As[lq + 2][lr] = ra0.z;
    As[lq + 3][lr] = ra0.w;
    As[lq + 16][lr] = ra1.x;
    As[lq + 17][lr] = ra1.y;
    As[lq + 18][lr] = ra1.z;
    As[lq + 19][lr] = ra1.w;
    *reinterpret_cast<float4*>(&Bs[bk0 + 0][bc0]) = rb0;
    *reinterpret_cast<float4*>(&Bs[bk0 + 8][bc0]) = rb1;
    *reinterpret_cast<float4*>(&Bs[bk0 + 16][bc0]) = rb2;
    *reinterpret_cast<float4*>(&Bs[bk0 + 24][bc0]) = rb3;
    __syncthreads();
    const bool more = (k0 + 32) < KMAX;
    if (more) {
      ra0 = loadA(k0 + 32, 0);
      ra1 = loadA(k0 + 32, 16);
      rb0 = loadB(k0 + 32, 0);
      rb1 = loadB(k0 + 32, 1);
      rb2 = loadB(k0 + 32, 2);
      rb3 = loadB(k0 + 32, 3);
    }
#pragma unroll
    for (int k = 0; k < 32; ++k) {
      float4 a4 = *reinterpret_cast<const float4*>(&As[k][ty * 4]);
      float4 b0 = *reinterpret_cast<const float4*>(&Bs[k][tx * 4]);
      float4 b1 = *reinterpret_cast<const float4*>(&Bs[k][64 + tx * 4]);
      const float a[4] = {a4.x, a4.y, a4.z, a4.w};
      const float bb[8] = {b0.x, b0.y, b0.z, b0.w, b1.x, b1.y, b1.z, b1.w};
#pragma unroll
      for (int i = 0; i < 4; ++i)
#pragma unroll
        for (int j = 0; j < 8; ++j) acc[i][j] = fmaf(a[i], bb[j], acc[i][j]);
    }
    __syncthreads();
  }
  float4 bi0 = *reinterpret_cast<const float4*>(&bias[n0 + tx * 4]);
  float4 bi1 = *reinterpret_cast<const float4*>(&bias[n0 + 64 + tx * 4]);
#pragma unroll
  for (int i = 0; i < 4; ++i) {
    int row = m0 + ty * 4 + i;
    if (row < M) {
      float4 o0 = make_float4(acc[i][0] + bi0.x, acc[i][1] + bi0.y, acc[i][2] + bi0.z,
                              acc[i][3] + bi0.w);
      float4 o1 = make_float4(acc[i][4] + bi1.x, acc[i][5] + bi1.y, acc[i][6] + bi1.z,
                              acc[i][7] + bi1.w);
      *reinterpret_cast<float4*>(&C[(size_t)row * 256 + n0 + tx * 4]) = o0;
      *reinterpret_cast<float4*>(&C[(size_t)row * 256 + n0 + 64 + tx * 4]) = o1;
    }
  }
}

// ============ aggmax: feature-chunked for per-XCD L2 residence, 8-deep MLP ============
__global__ __launch_bounds__(256) void k_aggmax(
    const float* __restrict__ xw, const int* __restrict__ row_ptr,
    const int* __restrict__ csr_src, float* __restrict__ agg, int N, int Nh) {
  const int cx = blockIdx.x & 7;
  const int chunk = cx & 3;
  const int half = cx >> 2;
  const int hw = threadIdx.x >> 5;
  const int sub = threadIdx.x & 31;
  const int node = half * Nh + blockIdx.y * 8 + hw;
  const int hi = half ? N : Nh;
  if (node >= hi) return;
  const float* base = xw + chunk * 32 + sub;
  const int beg = row_ptr[node], end = row_ptr[node + 1];
  float m0 = 0.f, m1 = 0.f, m2 = 0.f, m3 = 0.f;
  float m4 = 0.f, m5 = 0.f, m6 = 0.f, m7 = 0.f;
  int i = beg;
  for (; i + 7 < end; i += 8) {  // 8 independent gathers in flight
    int e0 = csr_src[i + 0], e1 = csr_src[i + 1], e2 = csr_src[i + 2], e3 = csr_src[i + 3];
    int e4 = csr_src[i + 4], e5 = csr_src[i + 5], e6 = csr_src[i + 6], e7 = csr_src[i + 7];
    float f0 = base[(size_t)e0 * 256];
    float f1 = base[(size_t)e1 * 256];
    float f2 = base[(size_t)e2 * 256];
    float f3 = base[(size_t)e3 * 256];
    float f4 = base[(size_t)e4 * 256];
    float f5 = base[(size_t)e5 * 256];
    float f6 = base[(size_t)e6 * 256];
    float f7 = base[(size_t)e7 * 256];
    m0 = fmaxf(m0, f0); m1 = fmaxf(m1, f1);
    m2 = fmaxf(m2, f2); m3 = fmaxf(m3, f3);
    m4 = fmaxf(m4, f4); m5 = fmaxf(m5, f5);
    m6 = fmaxf(m6, f6); m7 = fmaxf(m7, f7);
  }
  for (; i < end; ++i) m0 = fmaxf(m0, base[(size_t)csr_src[i] * 256]);
  m0 = fmaxf(fmaxf(fmaxf(m0, m1), fmaxf(m2, m3)),
             fmaxf(fmaxf(m4, m5), fmaxf(m6, m7)));
  agg[(size_t)node * 128 + chunk * 32 + sub] = m0;
}

// ============ update GEMM: h = relu(agg@W_agg + self + b_upd); fused u,v ============
// Register-prefetch pipeline (same pattern as k_gemm).
__global__ __launch_bounds__(256) void k_update2(
    const float* __restrict__ agg, const float* __restrict__ W_agg,
    const float* __restrict__ b_upd, const float* __restrict__ xw,
    const float* __restrict__ W_dec, const float* __restrict__ b_dec,
    float* __restrict__ h, float* __restrict__ u, float* __restrict__ v, int M) {
  __shared__ float AsT[32][33];
  __shared__ float Bs[32][128];
  const int m0 = blockIdx.x * 32;
  const int t = threadIdx.x;
  const int ty = t >> 5, tx = t & 31;
  const int lar = t >> 3, lac = (t & 7) << 2;
  const int arow = m0 + lar;
  const bool avalid = arow < M;
  const int br0 = t >> 5;

  auto loadAgg = [&](int k0) -> float4 {
    float4 av = make_float4(0.f, 0.f, 0.f, 0.f);
    if (avalid) av = *reinterpret_cast<const float4*>(&agg[(size_t)arow * 128 + k0 + lac]);
    return av;
  };

  float4 ra = loadAgg(0);
  float4 rb0 = *reinterpret_cast<const float4*>(&W_agg[(size_t)(br0 + 0) * 128 + tx * 4]);
  float4 rb1 = *reinterpret_cast<const float4*>(&W_agg[(size_t)(br0 + 8) * 128 + tx * 4]);
  float4 rb2 = *reinterpret_cast<const float4*>(&W_agg[(size_t)(br0 + 16) * 128 + tx * 4]);
  float4 rb3 = *reinterpret_cast<const float4*>(&W_agg[(size_t)(br0 + 24) * 128 + tx * 4]);

  float acc[4][4] = {};
  for (int k0 = 0; k0 < 128; k0 += 32) {
    AsT[lac + 0][lar] = ra.x;
    AsT[lac + 1][lar] = ra.y;
    AsT[lac + 2][lar] = ra.z;
    AsT[lac + 3][lar] = ra.w;
    *reinterpret_cast<float4*>(&Bs[br0 + 0][tx * 4]) = rb0;
    *reinterpret_cast<float4*>(&Bs[br0 + 8][tx * 4]) = rb1;
    *reinterpret_cast<float4*>(&Bs[br0 + 16][tx * 4]) = rb2;
    *reinterpret_cast<float4*>(&Bs[br0 + 24][tx * 4]) = rb3;
    __syncthreads();
    const bool more = (k0 + 32) < 128;
    if (more) {
      ra = loadAgg(k0 + 32);
      rb0 = *reinterpret_cast<const float4*>(&W_agg[(size_t)(k0 + 32 + br0 + 0) * 128 + tx * 4]);
      rb1 = *reinterpret_cast<const float4*>(&W_agg[(size_t)(k0 + 32 + br0 + 8) * 128 + tx * 4]);
      rb2 = *reinterpret_cast<const float4*>(&W_agg[(size_t)(k0 + 32 + br0 + 16) * 128 + tx * 4]);
      rb3 = *reinterpret_cast<const float4*>(&W_agg[(size_t)(k0 + 32 + br0 + 24) * 128 + tx * 4]);
    }
#pragma unroll
    for (int k = 0; k < 32; ++k) {
      float4 a4 = *reinterpret_cast<const float4*>(&AsT[k][ty * 4]);
      float4 b4 = *reinterpret_cast<const float4*>(&Bs[k][tx * 4]);
      const float aa[4] = {a4.x, a4.y, a4.z, a4.w};
      const float bb[4] = {b4.x, b4.y, b4.z, b4.w};
#pragma unroll
      for (int j = 0; j < 4; ++j)
#pragma unroll
        for (int c = 0; c < 4; ++c) acc[j][c] = fmaf(aa[j], bb[c], acc[j][c]);
    }
    __syncthreads();
  }
  const float4 bu4 = *reinterpret_cast<const float4*>(&b_upd[tx * 4]);
  const float4 wdu = *reinterpret_cast<const float4*>(&W_dec[tx * 4]);
  const float4 wdv = *reinterpret_cast<const float4*>(&W_dec[128 + tx * 4]);
  const float bd = b_dec[0];
#pragma unroll
  for (int j = 0; j < 4; ++j) {
    int row = m0 + ty * 4 + j;
    if (row >= M) continue;
    float4 sf = *reinterpret_cast<const float4*>(&xw[(size_t)row * 256 + 128 + tx * 4]);
    float4 h4;
    h4.x = fmaxf(acc[j][0] + sf.x + bu4.x, 0.f);
    h4.y = fmaxf(acc[j][1] + sf.y + bu4.y, 0.f);
    h4.z = fmaxf(acc[j][2] + sf.z + bu4.z, 0.f);
    h4.w = fmaxf(acc[j][3] + sf.w + bu4.w, 0.f);
    *reinterpret_cast<float4*>(&h[(size_t)row * 128 + tx * 4]) = h4;
    float up = h4.x * wdu.x + h4.y * wdu.y + h4.z * wdu.z + h4.w * wdu.w;
    float vp = h4.x * wdv.x + h4.y * wdv.y + h4.z * wdv.z + h4.w * wdv.w;
#pragma unroll
    for (int m = 16; m > 0; m >>= 1) {
      up += __shfl_xor(up, m);
      vp += __shfl_xor(vp, m);
    }
    if (tx == 0) {
      u[row] = up + bd;
      v[row] = vp;
    }
  }
}

// ============ fused losses: edge BCE partials + node y/max + y-BCE partials ============
#define GB 512
__global__ __launch_bounds__(256) void k_losses(
    const int* __restrict__ src, const int* __restrict__ dst, const float* __restrict__ u,
    const float* __restrict__ v, const int* __restrict__ tgt, const int* __restrict__ row_ptr,
    const int* __restrict__ csr_src, const int* __restrict__ row_ptr2,
    const int* __restrict__ csr_dst, const int* __restrict__ reach_row,
    float* __restrict__ ybuf, float* __restrict__ yout, int write_out,
    double* __restrict__ pe_slot, double* __restrict__ py_slot, int E, int N) {
  __shared__ double wsum[4];
  double term = 0.0;
  for (int e = blockIdx.x * blockDim.x + threadIdx.x; e < E; e += GB * 256) {
    float l = u[src[e]] + v[dst[e]];
    float xsel = (tgt[e] != 0) ? -l : l;
    float sp = log1pf(expf(xsel));
    term += (double)fmaxf(-sp, -100.0f);
  }
#pragma unroll
  for (int off = 32; off > 0; off >>= 1) term += __shfl_down(term, off);
  if ((threadIdx.x & 63) == 0) wsum[threadIdx.x >> 6] = term;
  __syncthreads();
  if (threadIdx.x == 0) pe_slot[blockIdx.x] = wsum[0] + wsum[1] + wsum[2] + wsum[3];
  __syncthreads();
  double c = 0.0;
  for (int n = blockIdx.x * blockDim.x + threadIdx.x; n < N; n += GB * 256) {
    float mu = -INFINITY, mv = -INFINITY;
    // incoming-u max, 4 gathers in flight
    {
      const int b1 = row_ptr[n], e1 = row_ptr[n + 1];
      int i = b1;
      float a0 = -INFINITY, a1 = -INFINITY, a2 = -INFINITY, a3 = -INFINITY;
      for (; i + 3 < e1; i += 4) {
        int s0 = csr_src[i], s1 = csr_src[i + 1], s2 = csr_src[i + 2], s3 = csr_src[i + 3];
        float u0 = u[s0], u1 = u[s1], u2 = u[s2], u3 = u[s3];
        a0 = fmaxf(a0, u0); a1 = fmaxf(a1, u1);
        a2 = fmaxf(a2, u2); a3 = fmaxf(a3, u3);
      }
      for (; i < e1; ++i) a0 = fmaxf(a0, u[csr_src[i]]);
      mu = fmaxf(fmaxf(a0, a1), fmaxf(a2, a3));
    }
    // outgoing-v max, 4 gathers in flight
    {
      const int b2 = row_ptr2[n], e2 = row_ptr2[n + 1];
      int i = b2;
      float a0 = -INFINITY, a1 = -INFINITY, a2 = -INFINITY, a3 = -INFINITY;
      for (; i + 3 < e2; i += 4) {
        int d0 = csr_dst[i], d1 = csr_dst[i + 1], d2 = csr_dst[i + 2], d3 = csr_dst[i + 3];
        float v0 = v[d0], v1 = v[d1], v2 = v[d2], v3 = v[d3];
        a0 = fmaxf(a0, v0); a1 = fmaxf(a1, v1);
        a2 = fmaxf(a2, v2); a3 = fmaxf(a3, v3);
      }
      for (; i < e2; ++i) a0 = fmaxf(a0, v[csr_dst[i]]);
      mv = fmaxf(fmaxf(a0, a1), fmaxf(a2, a3));
    }
    float m = fmaxf(mu + v[n], u[n] + mv);
    float a = 1.0f / (1.0f + expf(-m));
    float yv = (a >= 0.8f) ? 1.0f : 0.0f;
    ybuf[n] = yv;
    if (write_out) yout[n] = yv;
    if ((float)reach_row[n] != yv) c = 100.0;
  }
#pragma unroll
  for (int off = 32; off > 0; off >>= 1) c += __shfl_down(c, off);
  if ((threadIdx.x & 63) == 0) wsum[threadIdx.x >> 6] = c;
  __syncthreads();
  if (threadIdx.x == 0) py_slot[blockIdx.x] = wsum[0] + wsum[1] + wsum[2] + wsum[3];
}

__global__ void k_final(const double* __restrict__ pe, const double* __restrict__ py,
                        float* __restrict__ out4, int N, int E, int T) {
  __shared__ double le[8], ly[8];
  int lane = threadIdx.x;  // 64 threads
  for (int it = 0; it < T; ++it) {
    double s = 0.0;
    for (int i = lane; i < GB; i += 64) s += pe[(size_t)it * GB + i];
#pragma unroll
    for (int off = 32; off > 0; off >>= 1) s += __shfl_down(s, off);
    if (lane == 0) le[it] = s;
    double s2 = 0.0;
    for (int i = lane; i < GB; i += 64) s2 += py[(size_t)it * GB + i];
#pragma unroll
    for (int off = 32; off > 0; off >>= 1) s2 += __shfl_down(s2, off);
    if (lane == 0) ly[it] = s2;
  }
  __syncthreads();
  if (lane == 0) {
    float loss_x = (float)(-le[T - 1] / (double)E);
    float loss_h = 0.0f;
    for (int i = 0; i < T - 1; ++i) loss_h += (float)(-le[i] / (double)E);
    float yl_x = (float)(ly[T - 1] / (double)N);
    float yl_h = 0.0f;
    for (int i = 0; i < T - 1; ++i) yl_h += (float)(ly[i] / (double)N);
    out4[0] = loss_x;
    out4[1] = loss_h;
    out4[2] = yl_x;
    out4[3] = yl_h;
  }
}

// ============ launch ============
extern "C" void kernel_launch(void* const* d_in, const int* in_sizes, int n_in,
                              void* d_out, int out_size, void* d_ws, size_t ws_size,
                              hipStream_t stream) {
  const float* pos = (const float*)d_in[0];
  const float* s = (const float*)d_in[1];
  const int* eidx = (const int*)d_in[2];
  const int* pi = (const int*)d_in[3];
  const int* pi_h = (const int*)d_in[4];
  const int* reach = (const int*)d_in[5];
  const float* W_enc = (const float*)d_in[6];
  const float* b_enc = (const float*)d_in[7];
  const float* W_msg = (const float*)d_in[8];
  const float* b_msg = (const float*)d_in[9];
  const float* W_self = (const float*)d_in[10];
  const float* W_agg = (const float*)d_in[11];
  const float* b_upd = (const float*)d_in[12];
  const float* W_dec = (const float*)d_in[13];
  const float* b_dec = (const float*)d_in[14];

  const int N = in_sizes[0];
  const int E = in_sizes[3];
  const int T = in_sizes[4] / in_sizes[3];
  const int* src = eidx;
  const int* dst = eidx + E;

  char* w = (char*)d_ws;
  auto alloc = [&](size_t bytes) {
    char* p = w;
    w += (bytes + 255) & ~(size_t)255;
    return p;
  };
  float* xw = (float*)alloc((size_t)N * 256 * 4);
  float* agg = (float*)alloc((size_t)N * 128 * 4);
  float* h = (float*)alloc((size_t)N * 128 * 4);
  float* Wcat = (float*)alloc(256 * 256 * 4);
  float* bcat = (float*)alloc(256 * 4);
  float* u = (float*)alloc((size_t)N * 4);
  float* v = (float*)alloc((size_t)N * 4);
  float* ybuf = (float*)alloc((size_t)N * 4);
  int* cnt_d = (int*)alloc((size_t)N * 4);
  int* cnt_s = (int*)alloc((size_t)N * 4);
  int* row_ptr = (int*)alloc((size_t)(N + 1) * 4);
  int* row_ptr2 = (int*)alloc((size_t)(N + 1) * 4);
  int* csr_src = (int*)alloc((size_t)E * 4);
  int* csr_dst = (int*)alloc((size_t)E * 4);
  unsigned short* partial_d = (unsigned short*)alloc((size_t)CSR_B * N * 2);
  unsigned short* partial_s = (unsigned short*)alloc((size_t)CSR_B * N * 2);
  double* pe = (double*)alloc((size_t)T * GB * 8);
  double* py = (double*)alloc((size_t)T * GB * 8);
  const int NB2 = (N + SCAN_CHUNK - 1) / SCAN_CHUNK;
  int* bsum = (int*)alloc((size_t)2 * NB2 * 4);

  float* outy = (float*)d_out;
  float* out4 = outy + N;

  k_build_w<<<256, 256, 0, stream>>>(W_msg, W_self, b_msg, Wcat, bcat);

  const size_t lds2 = (size_t)2 * ((N + 1) >> 1) * 4;  // ~80 KB
  k_hist2<<<CSR_B, 512, lds2, stream>>>(eidx, E, N, partial_d, partial_s);
  k_colscan2<<<(2 * N + 255) / 256, 256, 0, stream>>>(partial_d, cnt_d, partial_s, cnt_s, N);
  k_bsum<<<dim3(NB2, 2), 256, 0, stream>>>(cnt_d, cnt_s, bsum, N, NB2);
  k_bscan<<<1, 64, 0, stream>>>(bsum, NB2);
  k_scanf<<<dim3(NB2, 2), 256, 0, stream>>>(cnt_d, cnt_s, bsum, row_ptr, row_ptr2, N, NB2);
  k_scatter2<<<CSR_B, 512, lds2, stream>>>(eidx, E, N, partial_d, row_ptr, csr_src, partial_s,
                                           row_ptr2, csr_dst);

  const int Nh = (N + 1) / 2;
  const int NB = (Nh + 7) / 8;

  const float* sfeat = s;
  for (int it = 0; it < T; ++it) {
    dim3 g1((N + 63) / 64, 2);
    if (it == 0)
      k_gemm<true><<<g1, 256, 0, stream>>>(pos, sfeat, h, W_enc, b_enc, Wcat, bcat, xw, N);
    else
      k_gemm<false><<<g1, 256, 0, stream>>>(pos, sfeat, h, W_enc, b_enc, Wcat, bcat, xw, N);

    k_aggmax<<<dim3(8, NB), 256, 0, stream>>>(xw, row_ptr, csr_src, agg, N, Nh);

    k_update2<<<(N + 31) / 32, 256, 0, stream>>>(agg, W_agg, b_upd, xw, W_dec, b_dec,
                                                 h, u, v, N);

    const int* tgt = (it < T - 1) ? (pi_h + (size_t)(it + 1) * E) : pi;
    const int* rrow = (it < T - 1) ? (reach + (size_t)(it + 1) * N) : (reach + (size_t)(T - 1) * N);
    k_losses<<<GB, 256, 0, stream>>>(src, dst, u, v, tgt, row_ptr, csr_src, row_ptr2, csr_dst,
                                     rrow, ybuf, outy, (it == T - 1) ? 1 : 0,
                                     pe + (size_t)it * GB, py + (size_t)it * GB, E, N);
    sfeat = ybuf;
  }
  k_final<<<1, 64, 0, stream>>>(pe, py, out4, N, E, T);
}